// Round 2
// baseline (3053.634 us; speedup 1.0000x reference)
//
#include <hip/hip_runtime.h>
#include <math.h>

#define N0   4096
#define D    512
#define NUM  8192
#define NCLS 100
#define KMIX 11

#define QT 32
#define CT 128
#define BK 32

// ---- workspace layout (float offsets) ---- total 618752 floats = 2.47 MB
#define OFF_NALL   0                       // [NUM]              8192
#define OFF_YALL   8192                    // [NUM]              8192
#define OFF_TK1S   16384                   // [N0][4*11]         180224
#define OFF_TK1I   196608                  // [N0][4*11] (int)   180224
#define OFF_TK2S   376832                  // [NUM][2*4]         65536
#define OFF_TK2I   442368                  // [NUM][2*4] (int)   65536
#define OFF_MUSUM  507904                  // [NCLS*D]           51200
#define OFF_CNT    559104                  // [NCLS]             100
#define OFF_KNN    559204                  // [1]
#define ZERO_N     51301                   // MUSUM..KNN inclusive
#define OFF_NMU    559232                  // [NCLS]
#define OFF_MUT    559360                  // [D][NCLS]          51200
#define OFF_RLOSS  610560                  // [NUM]

// Logical row r of the virtual [NUM][D] matrix: r<N0 -> x[r]; else
// lam*x[r-N0] + (1-lam)*x[perm[r-N0]]. ONE shared helper so every consumer
// produces bitwise-identical values (kNN ordering consistency).
__device__ __forceinline__ float4 ld_row4(const float* __restrict__ x, const int* __restrict__ perm,
                                          float lam, float om, int r, int col) {
  if (r < N0) {
    return *(const float4*)(x + (size_t)r * D + col);
  } else {
    int rr = r - N0;
    int p = perm[rr];
    float4 a = *(const float4*)(x + (size_t)rr * D + col);
    float4 b = *(const float4*)(x + (size_t)p * D + col);
    float4 m;
    m.x = lam * a.x + om * b.x;  m.y = lam * a.y + om * b.y;
    m.z = lam * a.z + om * b.z;  m.w = lam * a.w + om * b.w;
    return m;
  }
}

__global__ __launch_bounds__(256) void k_zero(float* __restrict__ p, int n) {
  int i = blockIdx.x * 256 + threadIdx.x;
  if (i < n) p[i] = 0.f;
}

__global__ __launch_bounds__(256) void k_y(const float* __restrict__ y, float* __restrict__ y_all) {
  int i = blockIdx.x * 256 + threadIdx.x;
  if (i < N0) y_all[i] = y[i];
}

// squared norms of all 8192 logical rows; one wave per row
__global__ __launch_bounds__(64) void k_norms(const float* __restrict__ x, const int* __restrict__ perm,
                                              const float* __restrict__ lam_p, float* __restrict__ n_all) {
  int i = blockIdx.x;
  float lam = lam_p[0], om = 1.0f - lam;
  int t = threadIdx.x;
  float4 a = ld_row4(x, perm, lam, om, i, t * 4);
  float4 b = ld_row4(x, perm, lam, om, i, t * 4 + 256);
  float s = a.x*a.x + a.y*a.y + a.z*a.z + a.w*a.w
          + b.x*b.x + b.y*b.y + b.z*b.z + b.w*b.w;
  #pragma unroll
  for (int o = 32; o > 0; o >>= 1) s += __shfl_down(s, o, 64);
  if (t == 0) n_all[i] = s;
}

// Fused score-GEMM + per-row top-K (smallest score = ||c||^2 - 2*dot; row-constant
// ||q||^2 dropped — ordering identical to reference distances).
// Queries are logical rows qstart + blockIdx.x*QT + (0..31); candidates are the
// logical rows [blockIdx.y*candPerSplit, +candPerSplit). Splits must not straddle
// the N0 boundary (each staged tile comes from one source).
template<int KK>
__global__ __launch_bounds__(256) void k_knn(const float* __restrict__ x, const int* __restrict__ perm,
                                             const float* __restrict__ lam_p, int qstart,
                                             const float* __restrict__ nC, int candPerSplit, int nsplits,
                                             float* __restrict__ outS, int* __restrict__ outI) {
  __shared__ float Qs[BK][QT + 4];
  __shared__ float Cs[BK][CT + 4];
  __shared__ float Ss[QT][CT + 4];

  int tid = threadIdx.x;
  float lam = lam_p[0], om = 1.0f - lam;
  int qbase = blockIdx.x * QT;
  int cb = blockIdx.y * candPerSplit;
  int ce = cb + candPerSplit;

  int cx = tid & 31;      // col group: cols cx*4..+3
  int ry = tid >> 5;      // row group: rows ry*4..+3
  int lr = tid >> 3;      // staging row 0..31
  int kc = (tid & 7) * 4; // staging k-chunk

  float ks[KK]; int ki[KK];
  #pragma unroll
  for (int q = 0; q < KK; q++) { ks[q] = 3.0e38f; ki[q] = 0x7fffffff; }

  for (int c0 = cb; c0 < ce; c0 += CT) {
    float acc[4][4];
    #pragma unroll
    for (int i = 0; i < 4; i++)
      #pragma unroll
      for (int j = 0; j < 4; j++) acc[i][j] = 0.f;

    for (int kk = 0; kk < D; kk += BK) {
      __syncthreads();
      {
        float4 v = ld_row4(x, perm, lam, om, qstart + qbase + lr, kk + kc);
        Qs[kc + 0][lr] = v.x; Qs[kc + 1][lr] = v.y; Qs[kc + 2][lr] = v.z; Qs[kc + 3][lr] = v.w;
      }
      #pragma unroll
      for (int rr = 0; rr < 4; rr++) {
        int r = lr + rr * 32;
        float4 v = ld_row4(x, perm, lam, om, c0 + r, kk + kc);
        Cs[kc + 0][r] = v.x; Cs[kc + 1][r] = v.y; Cs[kc + 2][r] = v.z; Cs[kc + 3][r] = v.w;
      }
      __syncthreads();
      #pragma unroll
      for (int k = 0; k < BK; k++) {
        float4 a4 = *(const float4*)&Qs[k][ry * 4];
        float4 b4 = *(const float4*)&Cs[k][cx * 4];
        float av[4] = {a4.x, a4.y, a4.z, a4.w};
        float bv[4] = {b4.x, b4.y, b4.z, b4.w};
        #pragma unroll
        for (int i = 0; i < 4; i++)
          #pragma unroll
          for (int j = 0; j < 4; j++) acc[i][j] += av[i] * bv[j];
      }
    }
    __syncthreads();
    {
      float4 nc4 = *(const float4*)&nC[c0 + cx * 4];
      float ncv[4] = {nc4.x, nc4.y, nc4.z, nc4.w};
      #pragma unroll
      for (int i = 0; i < 4; i++)
        #pragma unroll
        for (int j = 0; j < 4; j++)
          Ss[ry * 4 + i][cx * 4 + j] = ncv[j] - 2.0f * acc[i][j];
    }
    __syncthreads();
    if (tid < QT) {
      for (int c = 0; c < CT; c++) {
        float s = Ss[tid][c];
        int j = c0 + c;
        // reject vs current k-th (ties -> lower index, matching top_k stability)
        bool worse = (s > ks[KK - 1]) || (s == ks[KK - 1] && j > ki[KK - 1]);
        if (!worse) {
          ks[KK - 1] = s; ki[KK - 1] = j;
          #pragma unroll
          for (int p = KK - 1; p > 0; p--) {
            bool sw = (ks[p] < ks[p - 1]) || (ks[p] == ks[p - 1] && ki[p] < ki[p - 1]);
            if (sw) {
              float ts = ks[p]; ks[p] = ks[p - 1]; ks[p - 1] = ts;
              int ti = ki[p]; ki[p] = ki[p - 1]; ki[p - 1] = ti;
            }
          }
        }
      }
    }
  }

  if (tid < QT) {
    int row = qbase + tid;  // output row (0-based within this query set)
    size_t off = (size_t)row * (nsplits * KK) + (size_t)blockIdx.y * KK;
    #pragma unroll
    for (int q = 0; q < KK; q++) { outS[off + q] = ks[q]; outI[off + q] = ki[q]; }
  }
}

// merge 4 sorted 11-lists -> top-11 -> mode (most frequent, min on tie) -> y_ul
__global__ __launch_bounds__(256) void k_final1(const float* __restrict__ tks, const int* __restrict__ tki,
                                                const float* __restrict__ y, float* __restrict__ y_all) {
  int i = blockIdx.x * 256 + threadIdx.x;
  if (i >= N0) return;
  const float* sb = tks + (size_t)i * 44;
  const int* ib = tki + (size_t)i * 44;
  int p0 = 0, p1 = 0, p2 = 0, p3 = 0;
  float lab[KMIX];
  #pragma unroll
  for (int q = 0; q < KMIX; q++) {
    float bs = 3.0e38f; int bi = 0x7fffffff; int w = 0;
    if (p0 < 11) { float s = sb[p0];      int id = ib[p0];      if (s < bs || (s == bs && id < bi)) { bs = s; bi = id; w = 0; } }
    if (p1 < 11) { float s = sb[11 + p1]; int id = ib[11 + p1]; if (s < bs || (s == bs && id < bi)) { bs = s; bi = id; w = 1; } }
    if (p2 < 11) { float s = sb[22 + p2]; int id = ib[22 + p2]; if (s < bs || (s == bs && id < bi)) { bs = s; bi = id; w = 2; } }
    if (p3 < 11) { float s = sb[33 + p3]; int id = ib[33 + p3]; if (s < bs || (s == bs && id < bi)) { bs = s; bi = id; w = 3; } }
    if (w == 0) p0++; else if (w == 1) p1++; else if (w == 2) p2++; else p3++;
    lab[q] = y[bi];
  }
  float best = 3.0e38f; int bestc = 0;
  #pragma unroll
  for (int q = 0; q < KMIX; q++) {
    int c = 0;
    #pragma unroll
    for (int r = 0; r < KMIX; r++) c += (lab[r] == lab[q]) ? 1 : 0;
    if (c > bestc || (c == bestc && lab[q] < best)) { bestc = c; best = lab[q]; }
  }
  y_all[N0 + i] = best;
}

// per-class sums via atomics; 128 threads, float4 per thread
__global__ __launch_bounds__(128) void k_stats(const float* __restrict__ x, const int* __restrict__ perm,
                                               const float* __restrict__ lam_p, const float* __restrict__ y_all,
                                               float* __restrict__ mu_sum, float* __restrict__ counts) {
  int i = blockIdx.x;
  float lam = lam_p[0], om = 1.0f - lam;
  int c = (int)y_all[i];
  float* ms = mu_sum + (size_t)c * D;
  int t = threadIdx.x;
  float4 v = ld_row4(x, perm, lam, om, i, t * 4);
  atomicAdd(&ms[t * 4 + 0], v.x);
  atomicAdd(&ms[t * 4 + 1], v.y);
  atomicAdd(&ms[t * 4 + 2], v.z);
  atomicAdd(&ms[t * 4 + 3], v.w);
  if (t == 0) atomicAdd(&counts[c], 1.0f);
}

// mu (transposed) + ||mu||^2
__global__ __launch_bounds__(256) void k_mufin(const float* __restrict__ mu_sum, const float* __restrict__ counts,
                                               float* __restrict__ muT, float* __restrict__ nmu) {
  __shared__ float red[256];
  int c = blockIdx.x;
  float inv = 1.0f / fmaxf(counts[c], 1.0f);
  int t = threadIdx.x;
  float v0 = mu_sum[(size_t)c * D + t] * inv;
  float v1 = mu_sum[(size_t)c * D + t + 256] * inv;
  muT[(size_t)t * NCLS + c] = v0;
  muT[(size_t)(t + 256) * NCLS + c] = v1;
  red[t] = v0 * v0 + v1 * v1;
  __syncthreads();
  for (int o = 128; o > 0; o >>= 1) { if (t < o) red[t] += red[t + o]; __syncthreads(); }
  if (t == 0) nmu[c] = red[0];
}

// knn-regularizer finalize: merge 2 sorted 4-lists, drop rank-0 (self), mode of 3, MSE
__global__ __launch_bounds__(256) void k_final2(const float* __restrict__ t2s, const int* __restrict__ t2i,
                                                const float* __restrict__ y_all, float* __restrict__ knn_acc) {
  __shared__ float red[256];
  int i = blockIdx.x * 256 + threadIdx.x;
  float dd2 = 0.f;
  if (i < NUM) {
    const float* sA = t2s + (size_t)i * 8; const float* sB = sA + 4;
    const int* iA = t2i + (size_t)i * 8;   const int* iB = iA + 4;
    int pa = 0, pb = 0;
    int midx[4];
    #pragma unroll
    for (int q = 0; q < 4; q++) {
      float sa = (pa < 4) ? sA[pa] : 3.0e38f;
      float sb = (pb < 4) ? sB[pb] : 3.0e38f;
      int ia = (pa < 4) ? iA[pa] : 0x7fffffff;
      int ib = (pb < 4) ? iB[pb] : 0x7fffffff;
      bool ta = (sa < sb) || (sa == sb && ia < ib);
      midx[q] = ta ? ia : ib;
      if (ta) pa++; else pb++;
    }
    float l1 = y_all[midx[1]], l2 = y_all[midx[2]], l3 = y_all[midx[3]];
    int c1 = 1 + (int)(l2 == l1) + (int)(l3 == l1);
    int c2 = 1 + (int)(l1 == l2) + (int)(l3 == l2);
    int c3 = 1 + (int)(l1 == l3) + (int)(l2 == l3);
    int mc = c1 > c2 ? c1 : c2; mc = mc > c3 ? mc : c3;
    float mv = 3.0e38f;
    if (c1 == mc) mv = fminf(mv, l1);
    if (c2 == mc) mv = fminf(mv, l2);
    if (c3 == mc) mv = fminf(mv, l3);
    float d = mv - y_all[i];
    dd2 = d * d;
  }
  red[threadIdx.x] = dd2;
  __syncthreads();
  for (int o = 128; o > 0; o >>= 1) { if (threadIdx.x < o) red[threadIdx.x] += red[threadIdx.x + o]; __syncthreads(); }
  if (threadIdx.x == 0) atomicAdd(knn_acc, red[0]);
}

// GM loss per row; max-shifted exp reproduces f64 eps semantics through underflow
__global__ __launch_bounds__(128) void k_gm(const float* __restrict__ x, const int* __restrict__ perm,
                                            const float* __restrict__ lam_p, const float* __restrict__ y_all,
                                            const float* __restrict__ n_all, const float* __restrict__ muT,
                                            const float* __restrict__ nmu, const float* __restrict__ counts,
                                            float* __restrict__ row_loss) {
  __shared__ float red[128];
  int i = blockIdx.x;
  int t = threadIdx.x;
  float lam = lam_p[0], om = 1.0f - lam;
  bool valid = (t < NCLS) && (counts[t] > 0.f);
  float d2 = 3.0e38f;
  if (t < NCLS) {
    float dot = 0.f;
    for (int d = 0; d < D; d += 4) {
      float4 v = ld_row4(x, perm, lam, om, i, d);
      dot += v.x * muT[(size_t)(d + 0) * NCLS + t];
      dot += v.y * muT[(size_t)(d + 1) * NCLS + t];
      dot += v.z * muT[(size_t)(d + 2) * NCLS + t];
      dot += v.w * muT[(size_t)(d + 3) * NCLS + t];
    }
    d2 = n_all[i] + nmu[t] - 2.f * dot;
  }
  red[t] = valid ? d2 : 3.0e38f;
  __syncthreads();
  for (int o = 64; o > 0; o >>= 1) { if (t < o) red[t] = fminf(red[t], red[t + o]); __syncthreads(); }
  float m = red[0];
  __syncthreads();
  float e = valid ? expf(-0.5f * (d2 - m)) : 0.f;
  red[t] = e;
  __syncthreads();
  for (int o = 64; o > 0; o >>= 1) { if (t < o) red[t] += red[t + o]; __syncthreads(); }
  float S = red[0];
  __syncthreads();
  float E = expf(-0.5f * m);              // underflows to 0 exactly when f64 pi ~ 1e-80 -> both give pi=0
  float denom = E * S + 1e-15f;
  float pi = e * E / denom;
  pi = fminf(fmaxf(pi, 0.f), 1.f);
  int yc = (int)y_all[i];
  float term = pi * pi - 2.f * ((t == yc) ? pi : 0.f);
  red[t] = valid ? term : 0.f;
  __syncthreads();
  for (int o = 64; o > 0; o >>= 1) { if (t < o) red[t] += red[t + o]; __syncthreads(); }
  if (t == 0) row_loss[i] = red[0] + 1.0f;
}

__global__ __launch_bounds__(256) void k_final(const float* __restrict__ row_loss, const float* __restrict__ knn_acc,
                                               float* __restrict__ out) {
  __shared__ float red[256];
  int t = threadIdx.x;
  float s = 0.f;
  for (int i = t; i < NUM; i += 256) s += row_loss[i];
  red[t] = s;
  __syncthreads();
  for (int o = 128; o > 0; o >>= 1) { if (t < o) red[t] += red[t + o]; __syncthreads(); }
  if (t == 0) out[0] = red[0] / (float)NUM + 0.01f * (knn_acc[0] / (float)NUM);
}

extern "C" void kernel_launch(void* const* d_in, const int* in_sizes, int n_in,
                              void* d_out, int out_size, void* d_ws, size_t ws_size,
                              hipStream_t stream) {
  const float* x   = (const float*)d_in[0];
  const float* y   = (const float*)d_in[1];
  const float* lam = (const float*)d_in[2];
  const int* perm  = (const int*)d_in[3];
  float* ws = (float*)d_ws;

  float* n_all  = ws + OFF_NALL;
  float* y_all  = ws + OFF_YALL;
  float* tk1s   = ws + OFF_TK1S;
  int*   tk1i   = (int*)(ws + OFF_TK1I);
  float* tk2s   = ws + OFF_TK2S;
  int*   tk2i   = (int*)(ws + OFF_TK2I);
  float* mu_sum = ws + OFF_MUSUM;
  float* counts = ws + OFF_CNT;
  float* knn_acc= ws + OFF_KNN;
  float* nmu    = ws + OFF_NMU;
  float* muT    = ws + OFF_MUT;
  float* rloss  = ws + OFF_RLOSS;

  k_y<<<(N0 + 255) / 256, 256, 0, stream>>>(y, y_all);
  k_zero<<<(ZERO_N + 255) / 256, 256, 0, stream>>>(mu_sum, ZERO_N);
  k_norms<<<NUM, 64, 0, stream>>>(x, perm, lam, n_all);

  // mixup kNN: queries = x_ul (logical rows N0..NUM), candidates = x (0..N0), 4 splits
  dim3 g1(N0 / QT, 4);
  k_knn<KMIX><<<g1, 256, 0, stream>>>(x, perm, lam, N0, n_all, N0 / 4, 4, tk1s, tk1i);
  k_final1<<<(N0 + 255) / 256, 256, 0, stream>>>(tk1s, tk1i, y, y_all);

  k_stats<<<NUM, 128, 0, stream>>>(x, perm, lam, y_all, mu_sum, counts);
  k_mufin<<<NCLS, 256, 0, stream>>>(mu_sum, counts, muT, nmu);

  // knn regularizer: queries = all 8192 logical rows, candidates = all rows in
  // 2 splits aligned to the x / x_ul boundary, keep top-4 (self + 3)
  dim3 g2(NUM / QT, 2);
  k_knn<4><<<g2, 256, 0, stream>>>(x, perm, lam, 0, n_all, NUM / 2, 2, tk2s, tk2i);
  k_final2<<<NUM / 256, 256, 0, stream>>>(tk2s, tk2i, y_all, knn_acc);

  k_gm<<<NUM, 128, 0, stream>>>(x, perm, lam, y_all, n_all, muT, nmu, counts, rloss);
  k_final<<<1, 256, 0, stream>>>(rloss, knn_acc, (float*)d_out);
}

// Round 3
// 1440.278 us; speedup vs baseline: 2.1202x; 2.1202x over previous
//
#include <hip/hip_runtime.h>
#include <math.h>

#define N0   4096
#define D    512
#define NUM  8192
#define NCLS 100
#define KMIX 11

// ---- workspace layout (float offsets) ----
#define OFF_NALL   0            // [NUM]
#define OFF_YALL   8192         // [NUM]
#define OFF_RLOSS  16384        // [NUM]
#define OFF_KSQ    24576        // [NUM] (fast path per-row knn sq err)
#define OFF_MUSUM  32768        // [NCLS*D]
#define OFF_CNT    83968        // [NCLS] (+pad)
#define OFF_KNN    84096        // [1] slow-path scalar (+pad)
#define ZERO_N     51344        // MUSUM..KNN inclusive
#define OFF_NMU    84112        // [NCLS] (+pad)
#define OFF_MUT    84224        // [D][NCLS]
#define OFF_TK1S   135424       // fast: [4096][8*16] / slow: [4096][4*11]
#define OFF_TK1I   659712
#define OFF_TK2S   1184000      // fast: [8192][4*8] / slow: [8192][2*4]
#define OFF_TK2I   1446144
#define OFF_XH     1708288      // [NUM][512] f16 = 2097152 floats (16B-aligned)
#define TOTAL_F    3805440
#define NEED_BYTES ((size_t)TOTAL_F * 4)   // 15,221,760

typedef _Float16 half8 __attribute__((ext_vector_type(8)));
typedef _Float16 half4v __attribute__((ext_vector_type(4)));
typedef float f32x4 __attribute__((ext_vector_type(4)));

// Logical row r of the virtual [NUM][D] matrix: r<N0 -> x[r]; else
// lam*x[r-N0] + (1-lam)*x[perm[r-N0]]. One shared helper => bitwise-identical
// fp32 values in every consumer (kNN ordering consistency, matched ref in R2).
__device__ __forceinline__ float4 ld_row4(const float* __restrict__ x, const int* __restrict__ perm,
                                          float lam, float om, int r, int col) {
  if (r < N0) {
    return *(const float4*)(x + (size_t)r * D + col);
  } else {
    int rr = r - N0;
    int p = perm[rr];
    float4 a = *(const float4*)(x + (size_t)rr * D + col);
    float4 b = *(const float4*)(x + (size_t)p * D + col);
    float4 m;
    m.x = lam * a.x + om * b.x;  m.y = lam * a.y + om * b.y;
    m.z = lam * a.z + om * b.z;  m.w = lam * a.w + om * b.w;
    return m;
  }
}

__device__ __forceinline__ void gld_lds16(const _Float16* g, _Float16* l) {
  __builtin_amdgcn_global_load_lds(
      (const __attribute__((address_space(1))) void*)g,
      (__attribute__((address_space(3))) void*)l, 16, 0, 0);
}

__global__ __launch_bounds__(256) void k_zero(float* __restrict__ p, int n) {
  int i = blockIdx.x * 256 + threadIdx.x;
  if (i < n) p[i] = 0.f;
}

__global__ __launch_bounds__(256) void k_y(const float* __restrict__ y, float* __restrict__ y_all) {
  int i = blockIdx.x * 256 + threadIdx.x;
  if (i < N0) y_all[i] = y[i];
}

// exact fp32 squared norms of all 8192 logical rows
__global__ __launch_bounds__(64) void k_norms(const float* __restrict__ x, const int* __restrict__ perm,
                                              const float* __restrict__ lam_p, float* __restrict__ n_all) {
  int i = blockIdx.x;
  float lam = lam_p[0], om = 1.0f - lam;
  int t = threadIdx.x;
  float4 a = ld_row4(x, perm, lam, om, i, t * 4);
  float4 b = ld_row4(x, perm, lam, om, i, t * 4 + 256);
  float s = a.x*a.x + a.y*a.y + a.z*a.z + a.w*a.w
          + b.x*b.x + b.y*b.y + b.z*b.z + b.w*b.w;
  #pragma unroll
  for (int o = 32; o > 0; o >>= 1) s += __shfl_down(s, o, 64);
  if (t == 0) n_all[i] = s;
}

// materialize f16 copy of the virtual X (approx scores only)
__global__ __launch_bounds__(128) void k_cvt(const float* __restrict__ x, const int* __restrict__ perm,
                                             const float* __restrict__ lam_p, _Float16* __restrict__ Xh) {
  int i = blockIdx.x;
  float lam = lam_p[0], om = 1.0f - lam;
  int t = threadIdx.x;
  float4 v = ld_row4(x, perm, lam, om, i, t * 4);
  half4v h;
  h.x = (_Float16)v.x; h.y = (_Float16)v.y; h.z = (_Float16)v.z; h.w = (_Float16)v.w;
  *(half4v*)(Xh + (size_t)i * D + t * 4) = h;
}

// ---- MFMA approx-score kNN: 128x128 tiles, 64x64 per wave, f16 16x16x32 ----
// score = ||c||^2_fp32 - 2*dot_f16  (row-const ||q||^2 dropped). Per-row top-M
// (by (score, idx) lexicographic) per candidate split; exact re-rank later.
#define CT 128
template<int M>
__global__ __launch_bounds__(256) void k_knn_mfma(
    const _Float16* __restrict__ Xh, int qstart,
    const float* __restrict__ nC,
    int candPerSplit, int nsplits,
    float* __restrict__ outS, int* __restrict__ outI)
{
  __shared__ __align__(16) char smem[CT * 133 * 4];   // 68,096 B
  float* Ss = (float*)smem;                           // [cand][133] transposed scores
  _Float16* Qt = (_Float16*)smem;                     // [128][32] f16 (aliases Ss)
  _Float16* Ct = (_Float16*)(smem + 8192);            // [128][32] f16

  int tid = threadIdx.x;
  int wave = tid >> 6, lane = tid & 63;
  int wq = wave >> 1, wc = wave & 1;
  int col16 = lane & 15, quad = lane >> 4;

  int qb = blockIdx.x * CT;
  int cb = blockIdx.y * candPerSplit;

  // staging: wave handles 2 segs (16 rows each) per buffer; lane -> (row, k-grp)
  int s0 = wave * 2, s1 = wave * 2 + 1;
  int sr0 = s0 * 16 + (lane >> 2);
  int sr1 = s1 * 16 + (lane >> 2);
  int scol = (lane & 3) * 8;

  float ks[M]; int ki[M];
  #pragma unroll
  for (int q = 0; q < M; q++) { ks[q] = 3.0e38f; ki[q] = 0x7fffffff; }

  int r_scan = tid & 127, h_scan = tid >> 7;   // 2 scan threads per query row

  for (int c0 = 0; c0 < candPerSplit; c0 += CT) {
    f32x4 acc[4][4];
    #pragma unroll
    for (int i = 0; i < 4; i++)
      #pragma unroll
      for (int j = 0; j < 4; j++) acc[i][j] = (f32x4){0.f, 0.f, 0.f, 0.f};

    const _Float16* Qg = Xh + (size_t)(qstart + qb) * D;
    const _Float16* Cg = Xh + (size_t)(cb + c0) * D;

    for (int kk = 0; kk < D; kk += 32) {
      __syncthreads();  // prev consumers (MFMA reads / scan) done with smem
      gld_lds16(Qg + (size_t)sr0 * D + kk + scol, Qt + s0 * 512 + lane * 8);
      gld_lds16(Qg + (size_t)sr1 * D + kk + scol, Qt + s1 * 512 + lane * 8);
      gld_lds16(Cg + (size_t)sr0 * D + kk + scol, Ct + s0 * 512 + lane * 8);
      gld_lds16(Cg + (size_t)sr1 * D + kk + scol, Ct + s1 * 512 + lane * 8);
      __syncthreads();  // compiler drains vmcnt before barrier
      half8 a[4], b[4];
      #pragma unroll
      for (int i = 0; i < 4; i++)
        a[i] = *(const half8*)(Qt + (wq * 64 + i * 16 + col16) * 32 + quad * 8);
      #pragma unroll
      for (int j = 0; j < 4; j++)
        b[j] = *(const half8*)(Ct + (wc * 64 + j * 16 + col16) * 32 + quad * 8);
      #pragma unroll
      for (int i = 0; i < 4; i++)
        #pragma unroll
        for (int j = 0; j < 4; j++)
          acc[i][j] = __builtin_amdgcn_mfma_f32_16x16x32_f16(a[i], b[j], acc[i][j], 0, 0, 0);
    }
    __syncthreads();  // all waves done reading Qt/Ct before Ss overwrite
    // epilogue: C/D layout col=lane&15, row=quad*4+reg -> transposed store
    #pragma unroll
    for (int j = 0; j < 4; j++) {
      int c_local = wc * 64 + j * 16 + col16;
      float ncv = nC[cb + c0 + c_local];
      #pragma unroll
      for (int i = 0; i < 4; i++) {
        int q0 = wq * 64 + i * 16 + quad * 4;
        #pragma unroll
        for (int reg = 0; reg < 4; reg++)
          Ss[c_local * 133 + q0 + reg] = ncv - 2.0f * acc[i][j][reg];
      }
    }
    __syncthreads();
    // scan: conflict-free b32 reads (consecutive lanes -> consecutive queries)
    for (int c = h_scan * 64; c < h_scan * 64 + 64; c++) {
      float s = Ss[c * 133 + r_scan];
      int j = cb + c0 + c;
      bool take = (s < ks[M - 1]) || (s == ks[M - 1] && j < ki[M - 1]);
      if (take) {
        ks[M - 1] = s; ki[M - 1] = j;
        #pragma unroll
        for (int p = M - 1; p > 0; p--) {
          bool sw = (ks[p] < ks[p - 1]) || (ks[p] == ks[p - 1] && ki[p] < ki[p - 1]);
          if (sw) { float ts = ks[p]; ks[p] = ks[p - 1]; ks[p - 1] = ts;
                    int ti = ki[p]; ki[p] = ki[p - 1]; ki[p - 1] = ti; }
        }
      }
    }
  }

  // merge the two half-lists per row -> sorted top-M for this split
  __syncthreads();
  float* Ls = (float*)smem;                     // [2][128][M]
  int* Li = (int*)(smem + 2 * 128 * M * 4);     // [2][128][M]
  #pragma unroll
  for (int q = 0; q < M; q++) {
    Ls[(h_scan * 128 + r_scan) * M + q] = ks[q];
    Li[(h_scan * 128 + r_scan) * M + q] = ki[q];
  }
  __syncthreads();
  if (tid < 128) {
    const float* sA = Ls + (size_t)tid * M;
    const float* sB = Ls + (size_t)(128 + tid) * M;
    const int* iA = Li + (size_t)tid * M;
    const int* iB = Li + (size_t)(128 + tid) * M;
    int pa = 0, pb = 0;
    int row = qb + tid;
    size_t off = (size_t)row * ((size_t)nsplits * M) + (size_t)blockIdx.y * M;
    #pragma unroll
    for (int q = 0; q < M; q++) {
      float sa = (pa < M) ? sA[pa] : 3.0e38f;
      float sb2 = (pb < M) ? sB[pb] : 3.0e38f;
      int ia = (pa < M) ? iA[pa] : 0x7fffffff;
      int ib = (pb < M) ? iB[pb] : 0x7fffffff;
      bool ta = (sa < sb2) || (sa == sb2 && ia < ib);
      outS[off + q] = ta ? sa : sb2;
      outI[off + q] = ta ? ia : ib;
      if (ta) pa++; else pb++;
    }
  }
}

// exact fp32 re-rank for mixup: merge 8 split-lists -> top-16 approx -> exact
// distances -> sort by (score, idx) -> mode of 11 labels
__global__ __launch_bounds__(256) void k_rr1(const float* __restrict__ x, const int* __restrict__ perm,
                                             const float* __restrict__ lam_p,
                                             const float* __restrict__ tks, const int* __restrict__ tki,
                                             const float* __restrict__ n_all, const float* __restrict__ y,
                                             float* __restrict__ y_all) {
  __shared__ int sidx[16];
  __shared__ float sdot[16];
  int i = blockIdx.x;
  int t = threadIdx.x;
  float lam = lam_p[0], om = 1.f - lam;
  if (t == 0) {
    const float* sb = tks + (size_t)i * 128;
    const int* ib = tki + (size_t)i * 128;
    int p[8] = {0,0,0,0,0,0,0,0};
    for (int q = 0; q < 16; q++) {
      float bs = 3.0e38f; int bi = 0x7fffffff; int w = 0;
      #pragma unroll
      for (int li = 0; li < 8; li++) {
        if (p[li] < 16) {
          float s = sb[li * 16 + p[li]]; int id = ib[li * 16 + p[li]];
          if (s < bs || (s == bs && id < bi)) { bs = s; bi = id; w = li; }
        }
      }
      p[w]++;
      sidx[q] = bi;
    }
  }
  __syncthreads();
  int g = t >> 4, l16 = t & 15;
  int c = sidx[g];
  float dot = 0.f;
  for (int d0 = l16 * 4; d0 < D; d0 += 64) {
    float4 q4 = ld_row4(x, perm, lam, om, N0 + i, d0);
    float4 c4 = *(const float4*)(x + (size_t)c * D + d0);
    dot += q4.x*c4.x + q4.y*c4.y + q4.z*c4.z + q4.w*c4.w;
  }
  #pragma unroll
  for (int o = 8; o > 0; o >>= 1) dot += __shfl_down(dot, o, 16);
  if (l16 == 0) sdot[g] = n_all[c] - 2.f * dot;
  __syncthreads();
  if (t == 0) {
    float es[16]; int ei[16];
    for (int q = 0; q < 16; q++) { es[q] = sdot[q]; ei[q] = sidx[q]; }
    for (int a = 1; a < 16; a++) {
      float s = es[a]; int id = ei[a];
      int b = a - 1;
      while (b >= 0 && (es[b] > s || (es[b] == s && ei[b] > id))) {
        es[b + 1] = es[b]; ei[b + 1] = ei[b]; b--;
      }
      es[b + 1] = s; ei[b + 1] = id;
    }
    float lab[KMIX];
    for (int q = 0; q < KMIX; q++) lab[q] = y[ei[q]];
    float best = 3.0e38f; int bestc = 0;
    for (int q = 0; q < KMIX; q++) {
      int cnt = 0;
      for (int r = 0; r < KMIX; r++) cnt += (lab[r] == lab[q]) ? 1 : 0;
      if (cnt > bestc || (cnt == bestc && lab[q] < best)) { bestc = cnt; best = lab[q]; }
    }
    y_all[N0 + i] = best;
  }
}

// exact fp32 re-rank for knn reg: merge 4 split-lists -> top-8 -> exact -> sort,
// drop rank-0 (self), mode of 3, per-row sq err
__global__ __launch_bounds__(256) void k_rr2(const float* __restrict__ x, const int* __restrict__ perm,
                                             const float* __restrict__ lam_p,
                                             const float* __restrict__ tks, const int* __restrict__ tki,
                                             const float* __restrict__ n_all, const float* __restrict__ y_all,
                                             float* __restrict__ ksq) {
  __shared__ int sidx[8];
  __shared__ float sdot[8];
  int i = blockIdx.x;
  int t = threadIdx.x;
  float lam = lam_p[0], om = 1.f - lam;
  if (t == 0) {
    const float* sb = tks + (size_t)i * 32;
    const int* ib = tki + (size_t)i * 32;
    int p[4] = {0,0,0,0};
    for (int q = 0; q < 8; q++) {
      float bs = 3.0e38f; int bi = 0x7fffffff; int w = 0;
      #pragma unroll
      for (int li = 0; li < 4; li++) {
        if (p[li] < 8) {
          float s = sb[li * 8 + p[li]]; int id = ib[li * 8 + p[li]];
          if (s < bs || (s == bs && id < bi)) { bs = s; bi = id; w = li; }
        }
      }
      p[w]++;
      sidx[q] = bi;
    }
  }
  __syncthreads();
  int g = t >> 5, l32 = t & 31;
  int c = sidx[g];
  float dot = 0.f;
  for (int d0 = l32 * 4; d0 < D; d0 += 128) {
    float4 q4 = ld_row4(x, perm, lam, om, i, d0);
    float4 c4 = ld_row4(x, perm, lam, om, c, d0);
    dot += q4.x*c4.x + q4.y*c4.y + q4.z*c4.z + q4.w*c4.w;
  }
  #pragma unroll
  for (int o = 16; o > 0; o >>= 1) dot += __shfl_down(dot, o, 32);
  if (l32 == 0) sdot[g] = n_all[c] - 2.f * dot;
  __syncthreads();
  if (t == 0) {
    float es[8]; int ei[8];
    for (int q = 0; q < 8; q++) { es[q] = sdot[q]; ei[q] = sidx[q]; }
    for (int a = 1; a < 8; a++) {
      float s = es[a]; int id = ei[a];
      int b = a - 1;
      while (b >= 0 && (es[b] > s || (es[b] == s && ei[b] > id))) {
        es[b + 1] = es[b]; ei[b + 1] = ei[b]; b--;
      }
      es[b + 1] = s; ei[b + 1] = id;
    }
    float l1 = y_all[ei[1]], l2 = y_all[ei[2]], l3 = y_all[ei[3]];
    int c1 = 1 + (int)(l2 == l1) + (int)(l3 == l1);
    int c2 = 1 + (int)(l1 == l2) + (int)(l3 == l2);
    int c3 = 1 + (int)(l1 == l3) + (int)(l2 == l3);
    int mc = c1 > c2 ? c1 : c2; mc = mc > c3 ? mc : c3;
    float mv = 3.0e38f;
    if (c1 == mc) mv = fminf(mv, l1);
    if (c2 == mc) mv = fminf(mv, l2);
    if (c3 == mc) mv = fminf(mv, l3);
    float d = mv - y_all[i];
    ksq[i] = d * d;
  }
}

// per-class sums via atomics
__global__ __launch_bounds__(128) void k_stats(const float* __restrict__ x, const int* __restrict__ perm,
                                               const float* __restrict__ lam_p, const float* __restrict__ y_all,
                                               float* __restrict__ mu_sum, float* __restrict__ counts) {
  int i = blockIdx.x;
  float lam = lam_p[0], om = 1.0f - lam;
  int c = (int)y_all[i];
  float* ms = mu_sum + (size_t)c * D;
  int t = threadIdx.x;
  float4 v = ld_row4(x, perm, lam, om, i, t * 4);
  atomicAdd(&ms[t * 4 + 0], v.x);
  atomicAdd(&ms[t * 4 + 1], v.y);
  atomicAdd(&ms[t * 4 + 2], v.z);
  atomicAdd(&ms[t * 4 + 3], v.w);
  if (t == 0) atomicAdd(&counts[c], 1.0f);
}

__global__ __launch_bounds__(256) void k_mufin(const float* __restrict__ mu_sum, const float* __restrict__ counts,
                                               float* __restrict__ muT, float* __restrict__ nmu) {
  __shared__ float red[256];
  int c = blockIdx.x;
  float inv = 1.0f / fmaxf(counts[c], 1.0f);
  int t = threadIdx.x;
  float v0 = mu_sum[(size_t)c * D + t] * inv;
  float v1 = mu_sum[(size_t)c * D + t + 256] * inv;
  muT[(size_t)t * NCLS + c] = v0;
  muT[(size_t)(t + 256) * NCLS + c] = v1;
  red[t] = v0 * v0 + v1 * v1;
  __syncthreads();
  for (int o = 128; o > 0; o >>= 1) { if (t < o) red[t] += red[t + o]; __syncthreads(); }
  if (t == 0) nmu[c] = red[0];
}

// GM loss per row; max-shifted exp reproduces eps semantics through underflow
__global__ __launch_bounds__(128) void k_gm(const float* __restrict__ x, const int* __restrict__ perm,
                                            const float* __restrict__ lam_p, const float* __restrict__ y_all,
                                            const float* __restrict__ n_all, const float* __restrict__ muT,
                                            const float* __restrict__ nmu, const float* __restrict__ counts,
                                            float* __restrict__ row_loss) {
  __shared__ float red[128];
  int i = blockIdx.x;
  int t = threadIdx.x;
  float lam = lam_p[0], om = 1.0f - lam;
  bool valid = (t < NCLS) && (counts[t] > 0.f);
  float d2 = 3.0e38f;
  if (t < NCLS) {
    float dot = 0.f;
    for (int d = 0; d < D; d += 4) {
      float4 v = ld_row4(x, perm, lam, om, i, d);
      dot += v.x * muT[(size_t)(d + 0) * NCLS + t];
      dot += v.y * muT[(size_t)(d + 1) * NCLS + t];
      dot += v.z * muT[(size_t)(d + 2) * NCLS + t];
      dot += v.w * muT[(size_t)(d + 3) * NCLS + t];
    }
    d2 = n_all[i] + nmu[t] - 2.f * dot;
  }
  red[t] = valid ? d2 : 3.0e38f;
  __syncthreads();
  for (int o = 64; o > 0; o >>= 1) { if (t < o) red[t] = fminf(red[t], red[t + o]); __syncthreads(); }
  float m = red[0];
  __syncthreads();
  float e = valid ? expf(-0.5f * (d2 - m)) : 0.f;
  red[t] = e;
  __syncthreads();
  for (int o = 64; o > 0; o >>= 1) { if (t < o) red[t] += red[t + o]; __syncthreads(); }
  float S = red[0];
  __syncthreads();
  float E = expf(-0.5f * m);
  float denom = E * S + 1e-15f;
  float pi = e * E / denom;
  pi = fminf(fmaxf(pi, 0.f), 1.f);
  int yc = (int)y_all[i];
  float term = pi * pi - 2.f * ((t == yc) ? pi : 0.f);
  red[t] = valid ? term : 0.f;
  __syncthreads();
  for (int o = 64; o > 0; o >>= 1) { if (t < o) red[t] += red[t + o]; __syncthreads(); }
  if (t == 0) row_loss[i] = red[0] + 1.0f;
}

__global__ __launch_bounds__(256) void k_final_fast(const float* __restrict__ row_loss,
                                                    const float* __restrict__ ksq, float* __restrict__ out) {
  __shared__ float red[256];
  int t = threadIdx.x;
  float s = 0.f;
  for (int i = t; i < NUM; i += 256) s += row_loss[i] + 0.01f * ksq[i];
  red[t] = s;
  __syncthreads();
  for (int o = 128; o > 0; o >>= 1) { if (t < o) red[t] += red[t + o]; __syncthreads(); }
  if (t == 0) out[0] = red[0] / (float)NUM;
}

// ================= fp32 fallback path (R2, passed absmax 0.0) =================
#define QT 32
#define CTF 128
#define BKF 32

template<int KK>
__global__ __launch_bounds__(256) void k_knn_f32(const float* __restrict__ x, const int* __restrict__ perm,
                                                 const float* __restrict__ lam_p, int qstart,
                                                 const float* __restrict__ nC, int candPerSplit, int nsplits,
                                                 float* __restrict__ outS, int* __restrict__ outI) {
  __shared__ float Qs[BKF][QT + 4];
  __shared__ float Cs[BKF][CTF + 4];
  __shared__ float Sf[QT][CTF + 4];

  int tid = threadIdx.x;
  float lam = lam_p[0], om = 1.0f - lam;
  int qbase = blockIdx.x * QT;
  int cb = blockIdx.y * candPerSplit;
  int ce = cb + candPerSplit;

  int cx = tid & 31;
  int ry = tid >> 5;
  int lr = tid >> 3;
  int kc = (tid & 7) * 4;

  float ks[KK]; int ki[KK];
  #pragma unroll
  for (int q = 0; q < KK; q++) { ks[q] = 3.0e38f; ki[q] = 0x7fffffff; }

  for (int c0 = cb; c0 < ce; c0 += CTF) {
    float acc[4][4];
    #pragma unroll
    for (int i = 0; i < 4; i++)
      #pragma unroll
      for (int j = 0; j < 4; j++) acc[i][j] = 0.f;

    for (int kk = 0; kk < D; kk += BKF) {
      __syncthreads();
      {
        float4 v = ld_row4(x, perm, lam, om, qstart + qbase + lr, kk + kc);
        Qs[kc + 0][lr] = v.x; Qs[kc + 1][lr] = v.y; Qs[kc + 2][lr] = v.z; Qs[kc + 3][lr] = v.w;
      }
      #pragma unroll
      for (int rr = 0; rr < 4; rr++) {
        int r = lr + rr * 32;
        float4 v = ld_row4(x, perm, lam, om, c0 + r, kk + kc);
        Cs[kc + 0][r] = v.x; Cs[kc + 1][r] = v.y; Cs[kc + 2][r] = v.z; Cs[kc + 3][r] = v.w;
      }
      __syncthreads();
      #pragma unroll
      for (int k = 0; k < BKF; k++) {
        float4 a4 = *(const float4*)&Qs[k][ry * 4];
        float4 b4 = *(const float4*)&Cs[k][cx * 4];
        float av[4] = {a4.x, a4.y, a4.z, a4.w};
        float bv[4] = {b4.x, b4.y, b4.z, b4.w};
        #pragma unroll
        for (int i = 0; i < 4; i++)
          #pragma unroll
          for (int j = 0; j < 4; j++) acc[i][j] += av[i] * bv[j];
      }
    }
    __syncthreads();
    {
      float4 nc4 = *(const float4*)&nC[c0 + cx * 4];
      float ncv[4] = {nc4.x, nc4.y, nc4.z, nc4.w};
      #pragma unroll
      for (int i = 0; i < 4; i++)
        #pragma unroll
        for (int j = 0; j < 4; j++)
          Sf[ry * 4 + i][cx * 4 + j] = ncv[j] - 2.0f * acc[i][j];
    }
    __syncthreads();
    if (tid < QT) {
      for (int c = 0; c < CTF; c++) {
        float s = Sf[tid][c];
        int j = c0 + c;
        bool worse = (s > ks[KK - 1]) || (s == ks[KK - 1] && j > ki[KK - 1]);
        if (!worse) {
          ks[KK - 1] = s; ki[KK - 1] = j;
          #pragma unroll
          for (int p = KK - 1; p > 0; p--) {
            bool sw = (ks[p] < ks[p - 1]) || (ks[p] == ks[p - 1] && ki[p] < ki[p - 1]);
            if (sw) {
              float ts = ks[p]; ks[p] = ks[p - 1]; ks[p - 1] = ts;
              int ti = ki[p]; ki[p] = ki[p - 1]; ki[p - 1] = ti;
            }
          }
        }
      }
    }
  }

  if (tid < QT) {
    int row = qbase + tid;
    size_t off = (size_t)row * (nsplits * KK) + (size_t)blockIdx.y * KK;
    #pragma unroll
    for (int q = 0; q < KK; q++) { outS[off + q] = ks[q]; outI[off + q] = ki[q]; }
  }
}

__global__ __launch_bounds__(256) void k_final1(const float* __restrict__ tks, const int* __restrict__ tki,
                                                const float* __restrict__ y, float* __restrict__ y_all) {
  int i = blockIdx.x * 256 + threadIdx.x;
  if (i >= N0) return;
  const float* sb = tks + (size_t)i * 44;
  const int* ib = tki + (size_t)i * 44;
  int p0 = 0, p1 = 0, p2 = 0, p3 = 0;
  float lab[KMIX];
  #pragma unroll
  for (int q = 0; q < KMIX; q++) {
    float bs = 3.0e38f; int bi = 0x7fffffff; int w = 0;
    if (p0 < 11) { float s = sb[p0];      int id = ib[p0];      if (s < bs || (s == bs && id < bi)) { bs = s; bi = id; w = 0; } }
    if (p1 < 11) { float s = sb[11 + p1]; int id = ib[11 + p1]; if (s < bs || (s == bs && id < bi)) { bs = s; bi = id; w = 1; } }
    if (p2 < 11) { float s = sb[22 + p2]; int id = ib[22 + p2]; if (s < bs || (s == bs && id < bi)) { bs = s; bi = id; w = 2; } }
    if (p3 < 11) { float s = sb[33 + p3]; int id = ib[33 + p3]; if (s < bs || (s == bs && id < bi)) { bs = s; bi = id; w = 3; } }
    if (w == 0) p0++; else if (w == 1) p1++; else if (w == 2) p2++; else p3++;
    lab[q] = y[bi];
  }
  float best = 3.0e38f; int bestc = 0;
  #pragma unroll
  for (int q = 0; q < KMIX; q++) {
    int c = 0;
    #pragma unroll
    for (int r = 0; r < KMIX; r++) c += (lab[r] == lab[q]) ? 1 : 0;
    if (c > bestc || (c == bestc && lab[q] < best)) { bestc = c; best = lab[q]; }
  }
  y_all[N0 + i] = best;
}

__global__ __launch_bounds__(256) void k_final2(const float* __restrict__ t2s, const int* __restrict__ t2i,
                                                const float* __restrict__ y_all, float* __restrict__ knn_acc) {
  __shared__ float red[256];
  int i = blockIdx.x * 256 + threadIdx.x;
  float dd2 = 0.f;
  if (i < NUM) {
    const float* sA = t2s + (size_t)i * 8; const float* sB = sA + 4;
    const int* iA = t2i + (size_t)i * 8;   const int* iB = iA + 4;
    int pa = 0, pb = 0;
    int midx[4];
    #pragma unroll
    for (int q = 0; q < 4; q++) {
      float sa = (pa < 4) ? sA[pa] : 3.0e38f;
      float sb = (pb < 4) ? sB[pb] : 3.0e38f;
      int ia = (pa < 4) ? iA[pa] : 0x7fffffff;
      int ib = (pb < 4) ? iB[pb] : 0x7fffffff;
      bool ta = (sa < sb) || (sa == sb && ia < ib);
      midx[q] = ta ? ia : ib;
      if (ta) pa++; else pb++;
    }
    float l1 = y_all[midx[1]], l2 = y_all[midx[2]], l3 = y_all[midx[3]];
    int c1 = 1 + (int)(l2 == l1) + (int)(l3 == l1);
    int c2 = 1 + (int)(l1 == l2) + (int)(l3 == l2);
    int c3 = 1 + (int)(l1 == l3) + (int)(l2 == l3);
    int mc = c1 > c2 ? c1 : c2; mc = mc > c3 ? mc : c3;
    float mv = 3.0e38f;
    if (c1 == mc) mv = fminf(mv, l1);
    if (c2 == mc) mv = fminf(mv, l2);
    if (c3 == mc) mv = fminf(mv, l3);
    float d = mv - y_all[i];
    dd2 = d * d;
  }
  red[threadIdx.x] = dd2;
  __syncthreads();
  for (int o = 128; o > 0; o >>= 1) { if (threadIdx.x < o) red[threadIdx.x] += red[threadIdx.x + o]; __syncthreads(); }
  if (threadIdx.x == 0) atomicAdd(knn_acc, red[0]);
}

__global__ __launch_bounds__(256) void k_final_slow(const float* __restrict__ row_loss,
                                                    const float* __restrict__ knn_acc, float* __restrict__ out) {
  __shared__ float red[256];
  int t = threadIdx.x;
  float s = 0.f;
  for (int i = t; i < NUM; i += 256) s += row_loss[i];
  red[t] = s;
  __syncthreads();
  for (int o = 128; o > 0; o >>= 1) { if (t < o) red[t] += red[t + o]; __syncthreads(); }
  if (t == 0) out[0] = red[0] / (float)NUM + 0.01f * (knn_acc[0] / (float)NUM);
}

extern "C" void kernel_launch(void* const* d_in, const int* in_sizes, int n_in,
                              void* d_out, int out_size, void* d_ws, size_t ws_size,
                              hipStream_t stream) {
  const float* x   = (const float*)d_in[0];
  const float* y   = (const float*)d_in[1];
  const float* lam = (const float*)d_in[2];
  const int* perm  = (const int*)d_in[3];
  float* ws = (float*)d_ws;

  float* n_all  = ws + OFF_NALL;
  float* y_all  = ws + OFF_YALL;
  float* rloss  = ws + OFF_RLOSS;
  float* ksq    = ws + OFF_KSQ;
  float* mu_sum = ws + OFF_MUSUM;
  float* counts = ws + OFF_CNT;
  float* knn_acc= ws + OFF_KNN;
  float* nmu    = ws + OFF_NMU;
  float* muT    = ws + OFF_MUT;
  float* tk1s   = ws + OFF_TK1S;
  int*   tk1i   = (int*)(ws + OFF_TK1I);
  float* tk2s   = ws + OFF_TK2S;
  int*   tk2i   = (int*)(ws + OFF_TK2I);
  _Float16* Xh  = (_Float16*)(ws + OFF_XH);

  bool fast = ws_size >= NEED_BYTES;   // constant per-process: same path every call

  k_y<<<(N0 + 255) / 256, 256, 0, stream>>>(y, y_all);
  k_zero<<<(ZERO_N + 255) / 256, 256, 0, stream>>>(mu_sum, ZERO_N);
  k_norms<<<NUM, 64, 0, stream>>>(x, perm, lam, n_all);

  if (fast) {
    k_cvt<<<NUM, 128, 0, stream>>>(x, perm, lam, Xh);
    // mixup: queries rows N0..NUM, candidates rows 0..N0, 8 splits, top-16 approx
    k_knn_mfma<16><<<dim3(N0 / CT, 8), 256, 0, stream>>>(Xh, N0, n_all, N0 / 8, 8, tk1s, tk1i);
    k_rr1<<<N0, 256, 0, stream>>>(x, perm, lam, tk1s, tk1i, n_all, y, y_all);
    k_stats<<<NUM, 128, 0, stream>>>(x, perm, lam, y_all, mu_sum, counts);
    k_mufin<<<NCLS, 256, 0, stream>>>(mu_sum, counts, muT, nmu);
    // knn reg: all 8192 rows vs all, 4 splits, top-8 approx (self + margin)
    k_knn_mfma<8><<<dim3(NUM / CT, 4), 256, 0, stream>>>(Xh, 0, n_all, NUM / 4, 4, tk2s, tk2i);
    k_rr2<<<NUM, 256, 0, stream>>>(x, perm, lam, tk2s, tk2i, n_all, y_all, ksq);
    k_gm<<<NUM, 128, 0, stream>>>(x, perm, lam, y_all, n_all, muT, nmu, counts, rloss);
    k_final_fast<<<1, 256, 0, stream>>>(rloss, ksq, (float*)d_out);
  } else {
    dim3 g1(N0 / QT, 4);
    k_knn_f32<KMIX><<<g1, 256, 0, stream>>>(x, perm, lam, N0, n_all, N0 / 4, 4, tk1s, tk1i);
    k_final1<<<(N0 + 255) / 256, 256, 0, stream>>>(tk1s, tk1i, y, y_all);
    k_stats<<<NUM, 128, 0, stream>>>(x, perm, lam, y_all, mu_sum, counts);
    k_mufin<<<NCLS, 256, 0, stream>>>(mu_sum, counts, muT, nmu);
    dim3 g2(NUM / QT, 2);
    k_knn_f32<4><<<g2, 256, 0, stream>>>(x, perm, lam, 0, n_all, NUM / 2, 2, tk2s, tk2i);
    k_final2<<<NUM / 256, 256, 0, stream>>>(tk2s, tk2i, y_all, knn_acc);
    k_gm<<<NUM, 128, 0, stream>>>(x, perm, lam, y_all, n_all, muT, nmu, counts, rloss);
    k_final_slow<<<1, 256, 0, stream>>>(rloss, knn_acc, (float*)d_out);
  }
}

// Round 4
// 928.659 us; speedup vs baseline: 3.2882x; 1.5509x over previous
//
#include <hip/hip_runtime.h>
#include <math.h>

#define N0   4096
#define D    512
#define NUM  8192
#define NCLS 100
#define KMIX 11

// ---- workspace layout (float offsets) ---- (unchanged from R3: 15.2 MB)
#define OFF_NALL   0            // [NUM]
#define OFF_YALL   8192         // [NUM]
#define OFF_RLOSS  16384        // [NUM]
#define OFF_KSQ    24576        // [NUM]
#define OFF_MUSUM  32768        // [NCLS*D] (slow path only)
#define OFF_CNT    83968        // [NCLS]
#define OFF_KNN    84096        // [1] slow-path scalar
#define ZERO_N     51344        // MUSUM..KNN inclusive (slow path)
#define OFF_NMU    84112        // [NCLS]
#define OFF_MUT    84224        // [D][NCLS]
#define OFF_TK1S   135424       // fast: [4096][8*16] / slow: [4096][4*11]
#define OFF_TK1I   659712
#define OFF_TK2S   1184000      // fast: [8192][4*8] / slow: [8192][2*4]
#define OFF_TK2I   1446144
#define OFF_XH     1708288      // [NUM][512] f16
#define TOTAL_F    3805440
#define NEED_BYTES ((size_t)TOTAL_F * 4)   // 15,221,760

typedef _Float16 half8 __attribute__((ext_vector_type(8)));
typedef _Float16 half4v __attribute__((ext_vector_type(4)));
typedef float f32x4 __attribute__((ext_vector_type(4)));
typedef unsigned long long u64;

// Logical row r of the virtual [NUM][D] matrix (bitwise-identical everywhere)
__device__ __forceinline__ float4 ld_row4(const float* __restrict__ x, const int* __restrict__ perm,
                                          float lam, float om, int r, int col) {
  if (r < N0) {
    return *(const float4*)(x + (size_t)r * D + col);
  } else {
    int rr = r - N0;
    int p = perm[rr];
    float4 a = *(const float4*)(x + (size_t)rr * D + col);
    float4 b = *(const float4*)(x + (size_t)p * D + col);
    float4 m;
    m.x = lam * a.x + om * b.x;  m.y = lam * a.y + om * b.y;
    m.z = lam * a.z + om * b.z;  m.w = lam * a.w + om * b.w;
    return m;
  }
}

__device__ __forceinline__ void gld_lds16(const _Float16* g, _Float16* l) {
  __builtin_amdgcn_global_load_lds(
      (const __attribute__((address_space(1))) void*)g,
      (__attribute__((address_space(3))) void*)l, 16, 0, 0);
}

__device__ __forceinline__ unsigned sortable(float s) {
  unsigned u = __float_as_uint(s);
  return ((int)u < 0) ? ~u : (u | 0x80000000u);
}
__device__ __forceinline__ float unsortable(unsigned u) {
  return __uint_as_float(((int)u < 0) ? (u & 0x7fffffffu) : ~u);
}

__global__ __launch_bounds__(256) void k_zero(float* __restrict__ p, int n) {
  int i = blockIdx.x * 256 + threadIdx.x;
  if (i < n) p[i] = 0.f;
}

__global__ __launch_bounds__(256) void k_y(const float* __restrict__ y, float* __restrict__ y_all) {
  int i = blockIdx.x * 256 + threadIdx.x;
  if (i < N0) y_all[i] = y[i];
}

__global__ __launch_bounds__(64) void k_norms(const float* __restrict__ x, const int* __restrict__ perm,
                                              const float* __restrict__ lam_p, float* __restrict__ n_all) {
  int i = blockIdx.x;
  float lam = lam_p[0], om = 1.0f - lam;
  int t = threadIdx.x;
  float4 a = ld_row4(x, perm, lam, om, i, t * 4);
  float4 b = ld_row4(x, perm, lam, om, i, t * 4 + 256);
  float s = a.x*a.x + a.y*a.y + a.z*a.z + a.w*a.w
          + b.x*b.x + b.y*b.y + b.z*b.z + b.w*b.w;
  #pragma unroll
  for (int o = 32; o > 0; o >>= 1) s += __shfl_down(s, o, 64);
  if (t == 0) n_all[i] = s;
}

__global__ __launch_bounds__(128) void k_cvt(const float* __restrict__ x, const int* __restrict__ perm,
                                             const float* __restrict__ lam_p, _Float16* __restrict__ Xh) {
  int i = blockIdx.x;
  float lam = lam_p[0], om = 1.0f - lam;
  int t = threadIdx.x;
  float4 v = ld_row4(x, perm, lam, om, i, t * 4);
  half4v h;
  h.x = (_Float16)v.x; h.y = (_Float16)v.y; h.z = (_Float16)v.z; h.w = (_Float16)v.w;
  *(half4v*)(Xh + (size_t)i * D + t * 4) = h;
}

// ---- v2 MFMA kNN: 64q x 128c tile, fragment-ordered LDS, dbuf K-loop ----
// score = ||c||^2 - 2*dot_f16. Per-row top-M (lexicographic (score,idx) via
// packed u64 key) per candidate split; exact fp32 re-rank downstream.
// LDS: Ss [128][68] f32 (34,816 B); staging/merge aliased inside.
template<int M>
__global__ __launch_bounds__(256, 2) void k_knn2(
    const _Float16* __restrict__ Xh, int qstart,
    const float* __restrict__ nC, int candPerSplit, int nsplits,
    float* __restrict__ outS, int* __restrict__ outI)
{
  __shared__ __align__(16) char smem[34816];
  float* Ss = (float*)smem;           // [cand][68] transposed scores
  _Float16* St = (_Float16*)smem;     // staging: buf b at b*6144 halfs (Q 2048 + C 4096)
  u64* Lb = (u64*)smem;               // [4][64][M] merge lists

  int tid = threadIdx.x;
  int wave = tid >> 6, lane = tid & 63;
  int wq = wave >> 1, wc = wave & 1;        // 32q x 64c per wave
  int col16 = lane & 15, quad = lane >> 4;

  int qb0 = qstart + blockIdx.x * 64;
  int cb0 = blockIdx.y * candPerSplit;

  // staging sources (fragment order: lane l <- row l&15, k-chunk (l>>4)*8)
  const _Float16* Qrow = Xh + (size_t)(qb0 + wave * 16 + col16) * D + quad * 8;

  u64 keys[M];
  #pragma unroll
  for (int q = 0; q < M; q++) keys[q] = 0xFFFFFFFFFFFFFFFFULL;

  int r_scan = tid & 63;    // query row
  int h_scan = tid >> 6;    // candidate quarter

  for (int c0 = 0; c0 < candPerSplit; c0 += 128) {
    const _Float16* Crow0 = Xh + (size_t)(cb0 + c0 + wave * 32 + col16) * D + quad * 8;
    const _Float16* Crow1 = Crow0 + (size_t)16 * D;

    f32x4 acc[2][4];
    #pragma unroll
    for (int i = 0; i < 2; i++)
      #pragma unroll
      for (int j = 0; j < 4; j++) acc[i][j] = (f32x4){0.f, 0.f, 0.f, 0.f};

    // prologue: stage kk=0 into buf0
    gld_lds16(Qrow, St + wave * 512);
    gld_lds16(Crow0, St + 2048 + (2 * wave) * 512);
    gld_lds16(Crow1, St + 2048 + (2 * wave + 1) * 512);
    __syncthreads();

    #pragma unroll 4
    for (int t = 0; t < 16; t++) {
      int cur = t & 1;
      if (t < 15) {             // prefetch next K-chunk into other buffer
        int kk = (t + 1) * 32;
        _Float16* B = St + (cur ^ 1) * 6144;
        gld_lds16(Qrow + kk, B + wave * 512);
        gld_lds16(Crow0 + kk, B + 2048 + (2 * wave) * 512);
        gld_lds16(Crow1 + kk, B + 2048 + (2 * wave + 1) * 512);
      }
      const _Float16* Bc = St + cur * 6144;
      half8 a[2], b[4];
      #pragma unroll
      for (int i = 0; i < 2; i++)
        a[i] = *(const half8*)(Bc + (wq * 2 + i) * 512 + lane * 8);
      #pragma unroll
      for (int j = 0; j < 4; j++)
        b[j] = *(const half8*)(Bc + 2048 + (wc * 4 + j) * 512 + lane * 8);
      #pragma unroll
      for (int i = 0; i < 2; i++)
        #pragma unroll
        for (int j = 0; j < 4; j++)
          acc[i][j] = __builtin_amdgcn_mfma_f32_16x16x32_f16(a[i], b[j], acc[i][j], 0, 0, 0);
      __syncthreads();
    }

    // epilogue: transposed score store (C/D: col=lane&15, row=quad*4+reg)
    #pragma unroll
    for (int j = 0; j < 4; j++) {
      int c_local = wc * 64 + j * 16 + col16;
      float ncv = nC[cb0 + c0 + c_local];
      #pragma unroll
      for (int i = 0; i < 2; i++) {
        float4 st;
        st.x = ncv - 2.f * acc[i][j][0];
        st.y = ncv - 2.f * acc[i][j][1];
        st.z = ncv - 2.f * acc[i][j][2];
        st.w = ncv - 2.f * acc[i][j][3];
        *(float4*)&Ss[(size_t)c_local * 68 + wq * 32 + i * 16 + quad * 4] = st;
      }
    }
    __syncthreads();

    // scan: 4 threads per query row, 32 candidates each, conflict-free b32
    for (int c = h_scan * 32; c < h_scan * 32 + 32; c++) {
      float s = Ss[c * 68 + r_scan];
      u64 key = ((u64)sortable(s) << 32) | (unsigned)(cb0 + c0 + c);
      if (key < keys[M - 1]) {
        keys[M - 1] = key;
        #pragma unroll
        for (int p = M - 1; p > 0; p--) {
          if (keys[p] < keys[p - 1]) { u64 tmp = keys[p]; keys[p] = keys[p - 1]; keys[p - 1] = tmp; }
        }
      }
    }
    __syncthreads();   // Ss/staging free for next c-tile
  }

  // merge 4 partial lists per row -> sorted top-M for this split
  #pragma unroll
  for (int q = 0; q < M; q++)
    Lb[((size_t)h_scan * 64 + r_scan) * M + q] = keys[q];
  __syncthreads();
  if (tid < 64) {
    int p0 = 0, p1 = 0, p2 = 0, p3 = 0;
    const u64* L0 = Lb + (size_t)(0 * 64 + tid) * M;
    const u64* L1 = Lb + (size_t)(1 * 64 + tid) * M;
    const u64* L2 = Lb + (size_t)(2 * 64 + tid) * M;
    const u64* L3 = Lb + (size_t)(3 * 64 + tid) * M;
    int row = blockIdx.x * 64 + tid;
    size_t off = (size_t)row * ((size_t)nsplits * M) + (size_t)blockIdx.y * M;
    #pragma unroll
    for (int q = 0; q < M; q++) {
      u64 k0 = (p0 < M) ? L0[p0] : 0xFFFFFFFFFFFFFFFFULL;
      u64 k1 = (p1 < M) ? L1[p1] : 0xFFFFFFFFFFFFFFFFULL;
      u64 k2 = (p2 < M) ? L2[p2] : 0xFFFFFFFFFFFFFFFFULL;
      u64 k3 = (p3 < M) ? L3[p3] : 0xFFFFFFFFFFFFFFFFULL;
      u64 b01 = k0 < k1 ? k0 : k1;
      u64 b23 = k2 < k3 ? k2 : k3;
      u64 b = b01 < b23 ? b01 : b23;
      if (b == k0) p0++; else if (b == k1) p1++; else if (b == k2) p2++; else p3++;
      outS[off + q] = unsortable((unsigned)(b >> 32));
      outI[off + q] = (int)(unsigned)b;
    }
  }
}

// exact fp32 re-rank mixup: merge 8 split-lists(16) -> top-16 -> exact -> mode(11)
__global__ __launch_bounds__(256) void k_rr1(const float* __restrict__ x, const int* __restrict__ perm,
                                             const float* __restrict__ lam_p,
                                             const float* __restrict__ tks, const int* __restrict__ tki,
                                             const float* __restrict__ n_all, const float* __restrict__ y,
                                             float* __restrict__ y_all) {
  __shared__ int sidx[16];
  __shared__ float sdot[16];
  int i = blockIdx.x;
  int t = threadIdx.x;
  float lam = lam_p[0], om = 1.f - lam;
  if (t == 0) {
    const float* sb = tks + (size_t)i * 128;
    const int* ib = tki + (size_t)i * 128;
    int p[8] = {0,0,0,0,0,0,0,0};
    for (int q = 0; q < 16; q++) {
      float bs = 3.0e38f; int bi = 0x7fffffff; int w = 0;
      #pragma unroll
      for (int li = 0; li < 8; li++) {
        if (p[li] < 16) {
          float s = sb[li * 16 + p[li]]; int id = ib[li * 16 + p[li]];
          if (s < bs || (s == bs && id < bi)) { bs = s; bi = id; w = li; }
        }
      }
      p[w]++;
      sidx[q] = bi;
    }
  }
  __syncthreads();
  int g = t >> 4, l16 = t & 15;
  int c = sidx[g];
  float dot = 0.f;
  for (int d0 = l16 * 4; d0 < D; d0 += 64) {
    float4 q4 = ld_row4(x, perm, lam, om, N0 + i, d0);
    float4 c4 = *(const float4*)(x + (size_t)c * D + d0);
    dot += q4.x*c4.x + q4.y*c4.y + q4.z*c4.z + q4.w*c4.w;
  }
  #pragma unroll
  for (int o = 8; o > 0; o >>= 1) dot += __shfl_down(dot, o, 16);
  if (l16 == 0) sdot[g] = n_all[c] - 2.f * dot;
  __syncthreads();
  if (t == 0) {
    float es[16]; int ei[16];
    for (int q = 0; q < 16; q++) { es[q] = sdot[q]; ei[q] = sidx[q]; }
    for (int a = 1; a < 16; a++) {
      float s = es[a]; int id = ei[a];
      int b = a - 1;
      while (b >= 0 && (es[b] > s || (es[b] == s && ei[b] > id))) {
        es[b + 1] = es[b]; ei[b + 1] = ei[b]; b--;
      }
      es[b + 1] = s; ei[b + 1] = id;
    }
    float lab[KMIX];
    for (int q = 0; q < KMIX; q++) lab[q] = y[ei[q]];
    float best = 3.0e38f; int bestc = 0;
    for (int q = 0; q < KMIX; q++) {
      int cnt = 0;
      for (int r = 0; r < KMIX; r++) cnt += (lab[r] == lab[q]) ? 1 : 0;
      if (cnt > bestc || (cnt == bestc && lab[q] < best)) { bestc = cnt; best = lab[q]; }
    }
    y_all[N0 + i] = best;
  }
}

// exact fp32 re-rank knn reg: merge 4 split-lists(8) -> top-8 -> exact -> drop self, mode(3)
__global__ __launch_bounds__(256) void k_rr2(const float* __restrict__ x, const int* __restrict__ perm,
                                             const float* __restrict__ lam_p,
                                             const float* __restrict__ tks, const int* __restrict__ tki,
                                             const float* __restrict__ n_all, const float* __restrict__ y_all,
                                             float* __restrict__ ksq) {
  __shared__ int sidx[8];
  __shared__ float sdot[8];
  int i = blockIdx.x;
  int t = threadIdx.x;
  float lam = lam_p[0], om = 1.f - lam;
  if (t == 0) {
    const float* sb = tks + (size_t)i * 32;
    const int* ib = tki + (size_t)i * 32;
    int p[4] = {0,0,0,0};
    for (int q = 0; q < 8; q++) {
      float bs = 3.0e38f; int bi = 0x7fffffff; int w = 0;
      #pragma unroll
      for (int li = 0; li < 4; li++) {
        if (p[li] < 8) {
          float s = sb[li * 8 + p[li]]; int id = ib[li * 8 + p[li]];
          if (s < bs || (s == bs && id < bi)) { bs = s; bi = id; w = li; }
        }
      }
      p[w]++;
      sidx[q] = bi;
    }
  }
  __syncthreads();
  int g = t >> 5, l32 = t & 31;
  int c = sidx[g];
  float dot = 0.f;
  for (int d0 = l32 * 4; d0 < D; d0 += 128) {
    float4 q4 = ld_row4(x, perm, lam, om, i, d0);
    float4 c4 = ld_row4(x, perm, lam, om, c, d0);
    dot += q4.x*c4.x + q4.y*c4.y + q4.z*c4.z + q4.w*c4.w;
  }
  #pragma unroll
  for (int o = 16; o > 0; o >>= 1) dot += __shfl_down(dot, o, 32);
  if (l32 == 0) sdot[g] = n_all[c] - 2.f * dot;
  __syncthreads();
  if (t == 0) {
    float es[8]; int ei[8];
    for (int q = 0; q < 8; q++) { es[q] = sdot[q]; ei[q] = sidx[q]; }
    for (int a = 1; a < 8; a++) {
      float s = es[a]; int id = ei[a];
      int b = a - 1;
      while (b >= 0 && (es[b] > s || (es[b] == s && ei[b] > id))) {
        es[b + 1] = es[b]; ei[b + 1] = ei[b]; b--;
      }
      es[b + 1] = s; ei[b + 1] = id;
    }
    float l1 = y_all[ei[1]], l2 = y_all[ei[2]], l3 = y_all[ei[3]];
    int c1 = 1 + (int)(l2 == l1) + (int)(l3 == l1);
    int c2 = 1 + (int)(l1 == l2) + (int)(l3 == l2);
    int c3 = 1 + (int)(l1 == l3) + (int)(l2 == l3);
    int mc = c1 > c2 ? c1 : c2; mc = mc > c3 ? mc : c3;
    float mv = 3.0e38f;
    if (c1 == mc) mv = fminf(mv, l1);
    if (c2 == mc) mv = fminf(mv, l2);
    if (c3 == mc) mv = fminf(mv, l3);
    float d = mv - y_all[i];
    ksq[i] = d * d;
  }
}

// per-class mean via LDS row-list (no global atomics); fuses k_stats+k_mufin
__global__ __launch_bounds__(256) void k_stats2(const float* __restrict__ x, const int* __restrict__ perm,
                                                const float* __restrict__ lam_p, const float* __restrict__ y_all,
                                                float* __restrict__ muT, float* __restrict__ nmu,
                                                float* __restrict__ counts) {
  __shared__ int cnt;
  __shared__ int lst[NUM];
  __shared__ int lstp[NUM];
  __shared__ float red[256];
  int c = blockIdx.x;
  int t = threadIdx.x;
  float lam = lam_p[0], om = 1.f - lam;
  float fc = (float)c;
  if (t == 0) cnt = 0;
  __syncthreads();
  for (int i = t; i < NUM; i += 256) {
    if (y_all[i] == fc) {
      int pos = atomicAdd(&cnt, 1);
      lst[pos] = i;
      lstp[pos] = (i >= N0) ? perm[i - N0] : 0;
    }
  }
  __syncthreads();
  int n = cnt;
  float a0 = 0.f, a1 = 0.f;
  for (int m = 0; m < n; m++) {
    int i = lst[m];
    if (i < N0) {
      a0 += x[(size_t)i * D + t];
      a1 += x[(size_t)i * D + t + 256];
    } else {
      int rr = i - N0, p = lstp[m];
      a0 += lam * x[(size_t)rr * D + t] + om * x[(size_t)p * D + t];
      a1 += lam * x[(size_t)rr * D + t + 256] + om * x[(size_t)p * D + t + 256];
    }
  }
  float inv = 1.f / fmaxf((float)n, 1.f);
  float v0 = a0 * inv, v1 = a1 * inv;
  muT[(size_t)t * NCLS + c] = v0;
  muT[(size_t)(t + 256) * NCLS + c] = v1;
  red[t] = v0 * v0 + v1 * v1;
  __syncthreads();
  for (int o = 128; o > 0; o >>= 1) { if (t < o) red[t] += red[t + o]; __syncthreads(); }
  if (t == 0) { nmu[c] = red[0]; counts[c] = (float)n; }
}

// GM loss per row; max-shifted exp reproduces eps semantics through underflow
__global__ __launch_bounds__(128) void k_gm(const float* __restrict__ x, const int* __restrict__ perm,
                                            const float* __restrict__ lam_p, const float* __restrict__ y_all,
                                            const float* __restrict__ n_all, const float* __restrict__ muT,
                                            const float* __restrict__ nmu, const float* __restrict__ counts,
                                            float* __restrict__ row_loss) {
  __shared__ float red[128];
  int i = blockIdx.x;
  int t = threadIdx.x;
  float lam = lam_p[0], om = 1.0f - lam;
  bool valid = (t < NCLS) && (counts[t] > 0.f);
  float d2 = 3.0e38f;
  if (t < NCLS) {
    float dot = 0.f;
    for (int d = 0; d < D; d += 4) {
      float4 v = ld_row4(x, perm, lam, om, i, d);
      dot += v.x * muT[(size_t)(d + 0) * NCLS + t];
      dot += v.y * muT[(size_t)(d + 1) * NCLS + t];
      dot += v.z * muT[(size_t)(d + 2) * NCLS + t];
      dot += v.w * muT[(size_t)(d + 3) * NCLS + t];
    }
    d2 = n_all[i] + nmu[t] - 2.f * dot;
  }
  red[t] = valid ? d2 : 3.0e38f;
  __syncthreads();
  for (int o = 64; o > 0; o >>= 1) { if (t < o) red[t] = fminf(red[t], red[t + o]); __syncthreads(); }
  float m = red[0];
  __syncthreads();
  float e = valid ? expf(-0.5f * (d2 - m)) : 0.f;
  red[t] = e;
  __syncthreads();
  for (int o = 64; o > 0; o >>= 1) { if (t < o) red[t] += red[t + o]; __syncthreads(); }
  float S = red[0];
  __syncthreads();
  float E = expf(-0.5f * m);
  float denom = E * S + 1e-15f;
  float pi = e * E / denom;
  pi = fminf(fmaxf(pi, 0.f), 1.f);
  int yc = (int)y_all[i];
  float term = pi * pi - 2.f * ((t == yc) ? pi : 0.f);
  red[t] = valid ? term : 0.f;
  __syncthreads();
  for (int o = 64; o > 0; o >>= 1) { if (t < o) red[t] += red[t + o]; __syncthreads(); }
  if (t == 0) row_loss[i] = red[0] + 1.0f;
}

__global__ __launch_bounds__(256) void k_final_fast(const float* __restrict__ row_loss,
                                                    const float* __restrict__ ksq, float* __restrict__ out) {
  __shared__ float red[256];
  int t = threadIdx.x;
  float s = 0.f;
  for (int i = t; i < NUM; i += 256) s += row_loss[i] + 0.01f * ksq[i];
  red[t] = s;
  __syncthreads();
  for (int o = 128; o > 0; o >>= 1) { if (t < o) red[t] += red[t + o]; __syncthreads(); }
  if (t == 0) out[0] = red[0] / (float)NUM;
}

// ================= fp32 fallback path (R2, passed absmax 0.0) =================
#define QT 32
#define CTF 128
#define BKF 32

template<int KK>
__global__ __launch_bounds__(256) void k_knn_f32(const float* __restrict__ x, const int* __restrict__ perm,
                                                 const float* __restrict__ lam_p, int qstart,
                                                 const float* __restrict__ nC, int candPerSplit, int nsplits,
                                                 float* __restrict__ outS, int* __restrict__ outI) {
  __shared__ float Qs[BKF][QT + 4];
  __shared__ float Cs[BKF][CTF + 4];
  __shared__ float Sf[QT][CTF + 4];

  int tid = threadIdx.x;
  float lam = lam_p[0], om = 1.0f - lam;
  int qbase = blockIdx.x * QT;
  int cb = blockIdx.y * candPerSplit;
  int ce = cb + candPerSplit;

  int cx = tid & 31;
  int ry = tid >> 5;
  int lr = tid >> 3;
  int kc = (tid & 7) * 4;

  float ks[KK]; int ki[KK];
  #pragma unroll
  for (int q = 0; q < KK; q++) { ks[q] = 3.0e38f; ki[q] = 0x7fffffff; }

  for (int c0 = cb; c0 < ce; c0 += CTF) {
    float acc[4][4];
    #pragma unroll
    for (int i = 0; i < 4; i++)
      #pragma unroll
      for (int j = 0; j < 4; j++) acc[i][j] = 0.f;

    for (int kk = 0; kk < D; kk += BKF) {
      __syncthreads();
      {
        float4 v = ld_row4(x, perm, lam, om, qstart + qbase + lr, kk + kc);
        Qs[kc + 0][lr] = v.x; Qs[kc + 1][lr] = v.y; Qs[kc + 2][lr] = v.z; Qs[kc + 3][lr] = v.w;
      }
      #pragma unroll
      for (int rr = 0; rr < 4; rr++) {
        int r = lr + rr * 32;
        float4 v = ld_row4(x, perm, lam, om, c0 + r, kk + kc);
        Cs[kc + 0][r] = v.x; Cs[kc + 1][r] = v.y; Cs[kc + 2][r] = v.z; Cs[kc + 3][r] = v.w;
      }
      __syncthreads();
      #pragma unroll
      for (int k = 0; k < BKF; k++) {
        float4 a4 = *(const float4*)&Qs[k][ry * 4];
        float4 b4 = *(const float4*)&Cs[k][cx * 4];
        float av[4] = {a4.x, a4.y, a4.z, a4.w};
        float bv[4] = {b4.x, b4.y, b4.z, b4.w};
        #pragma unroll
        for (int i = 0; i < 4; i++)
          #pragma unroll
          for (int j = 0; j < 4; j++) acc[i][j] += av[i] * bv[j];
      }
    }
    __syncthreads();
    {
      float4 nc4 = *(const float4*)&nC[c0 + cx * 4];
      float ncv[4] = {nc4.x, nc4.y, nc4.z, nc4.w};
      #pragma unroll
      for (int i = 0; i < 4; i++)
        #pragma unroll
        for (int j = 0; j < 4; j++)
          Sf[ry * 4 + i][cx * 4 + j] = ncv[j] - 2.0f * acc[i][j];
    }
    __syncthreads();
    if (tid < QT) {
      for (int c = 0; c < CTF; c++) {
        float s = Sf[tid][c];
        int j = c0 + c;
        bool worse = (s > ks[KK - 1]) || (s == ks[KK - 1] && j > ki[KK - 1]);
        if (!worse) {
          ks[KK - 1] = s; ki[KK - 1] = j;
          #pragma unroll
          for (int p = KK - 1; p > 0; p--) {
            bool sw = (ks[p] < ks[p - 1]) || (ks[p] == ks[p - 1] && ki[p] < ki[p - 1]);
            if (sw) {
              float ts = ks[p]; ks[p] = ks[p - 1]; ks[p - 1] = ts;
              int ti = ki[p]; ki[p] = ki[p - 1]; ki[p - 1] = ti;
            }
          }
        }
      }
    }
  }

  if (tid < QT) {
    int row = qbase + tid;
    size_t off = (size_t)row * (nsplits * KK) + (size_t)blockIdx.y * KK;
    #pragma unroll
    for (int q = 0; q < KK; q++) { outS[off + q] = ks[q]; outI[off + q] = ki[q]; }
  }
}

__global__ __launch_bounds__(256) void k_final1(const float* __restrict__ tks, const int* __restrict__ tki,
                                                const float* __restrict__ y, float* __restrict__ y_all) {
  int i = blockIdx.x * 256 + threadIdx.x;
  if (i >= N0) return;
  const float* sb = tks + (size_t)i * 44;
  const int* ib = tki + (size_t)i * 44;
  int p0 = 0, p1 = 0, p2 = 0, p3 = 0;
  float lab[KMIX];
  #pragma unroll
  for (int q = 0; q < KMIX; q++) {
    float bs = 3.0e38f; int bi = 0x7fffffff; int w = 0;
    if (p0 < 11) { float s = sb[p0];      int id = ib[p0];      if (s < bs || (s == bs && id < bi)) { bs = s; bi = id; w = 0; } }
    if (p1 < 11) { float s = sb[11 + p1]; int id = ib[11 + p1]; if (s < bs || (s == bs && id < bi)) { bs = s; bi = id; w = 1; } }
    if (p2 < 11) { float s = sb[22 + p2]; int id = ib[22 + p2]; if (s < bs || (s == bs && id < bi)) { bs = s; bi = id; w = 2; } }
    if (p3 < 11) { float s = sb[33 + p3]; int id = ib[33 + p3]; if (s < bs || (s == bs && id < bi)) { bs = s; bi = id; w = 3; } }
    if (w == 0) p0++; else if (w == 1) p1++; else if (w == 2) p2++; else p3++;
    lab[q] = y[bi];
  }
  float best = 3.0e38f; int bestc = 0;
  #pragma unroll
  for (int q = 0; q < KMIX; q++) {
    int c = 0;
    #pragma unroll
    for (int r = 0; r < KMIX; r++) c += (lab[r] == lab[q]) ? 1 : 0;
    if (c > bestc || (c == bestc && lab[q] < best)) { bestc = c; best = lab[q]; }
  }
  y_all[N0 + i] = best;
}

__global__ __launch_bounds__(128) void k_stats(const float* __restrict__ x, const int* __restrict__ perm,
                                               const float* __restrict__ lam_p, const float* __restrict__ y_all,
                                               float* __restrict__ mu_sum, float* __restrict__ counts) {
  int i = blockIdx.x;
  float lam = lam_p[0], om = 1.0f - lam;
  int c = (int)y_all[i];
  float* ms = mu_sum + (size_t)c * D;
  int t = threadIdx.x;
  float4 v = ld_row4(x, perm, lam, om, i, t * 4);
  atomicAdd(&ms[t * 4 + 0], v.x);
  atomicAdd(&ms[t * 4 + 1], v.y);
  atomicAdd(&ms[t * 4 + 2], v.z);
  atomicAdd(&ms[t * 4 + 3], v.w);
  if (t == 0) atomicAdd(&counts[c], 1.0f);
}

__global__ __launch_bounds__(256) void k_mufin(const float* __restrict__ mu_sum, const float* __restrict__ counts,
                                               float* __restrict__ muT, float* __restrict__ nmu) {
  __shared__ float red[256];
  int c = blockIdx.x;
  float inv = 1.0f / fmaxf(counts[c], 1.0f);
  int t = threadIdx.x;
  float v0 = mu_sum[(size_t)c * D + t] * inv;
  float v1 = mu_sum[(size_t)c * D + t + 256] * inv;
  muT[(size_t)t * NCLS + c] = v0;
  muT[(size_t)(t + 256) * NCLS + c] = v1;
  red[t] = v0 * v0 + v1 * v1;
  __syncthreads();
  for (int o = 128; o > 0; o >>= 1) { if (t < o) red[t] += red[t + o]; __syncthreads(); }
  if (t == 0) nmu[c] = red[0];
}

__global__ __launch_bounds__(256) void k_final2(const float* __restrict__ t2s, const int* __restrict__ t2i,
                                                const float* __restrict__ y_all, float* __restrict__ knn_acc) {
  __shared__ float red[256];
  int i = blockIdx.x * 256 + threadIdx.x;
  float dd2 = 0.f;
  if (i < NUM) {
    const float* sA = t2s + (size_t)i * 8; const float* sB = sA + 4;
    const int* iA = t2i + (size_t)i * 8;   const int* iB = iA + 4;
    int pa = 0, pb = 0;
    int midx[4];
    #pragma unroll
    for (int q = 0; q < 4; q++) {
      float sa = (pa < 4) ? sA[pa] : 3.0e38f;
      float sb = (pb < 4) ? sB[pb] : 3.0e38f;
      int ia = (pa < 4) ? iA[pa] : 0x7fffffff;
      int ib = (pb < 4) ? iB[pb] : 0x7fffffff;
      bool ta = (sa < sb) || (sa == sb && ia < ib);
      midx[q] = ta ? ia : ib;
      if (ta) pa++; else pb++;
    }
    float l1 = y_all[midx[1]], l2 = y_all[midx[2]], l3 = y_all[midx[3]];
    int c1 = 1 + (int)(l2 == l1) + (int)(l3 == l1);
    int c2 = 1 + (int)(l1 == l2) + (int)(l3 == l2);
    int c3 = 1 + (int)(l1 == l3) + (int)(l2 == l3);
    int mc = c1 > c2 ? c1 : c2; mc = mc > c3 ? mc : c3;
    float mv = 3.0e38f;
    if (c1 == mc) mv = fminf(mv, l1);
    if (c2 == mc) mv = fminf(mv, l2);
    if (c3 == mc) mv = fminf(mv, l3);
    float d = mv - y_all[i];
    dd2 = d * d;
  }
  red[threadIdx.x] = dd2;
  __syncthreads();
  for (int o = 128; o > 0; o >>= 1) { if (threadIdx.x < o) red[threadIdx.x] += red[threadIdx.x + o]; __syncthreads(); }
  if (threadIdx.x == 0) atomicAdd(knn_acc, red[0]);
}

__global__ __launch_bounds__(256) void k_final_slow(const float* __restrict__ row_loss,
                                                    const float* __restrict__ knn_acc, float* __restrict__ out) {
  __shared__ float red[256];
  int t = threadIdx.x;
  float s = 0.f;
  for (int i = t; i < NUM; i += 256) s += row_loss[i];
  red[t] = s;
  __syncthreads();
  for (int o = 128; o > 0; o >>= 1) { if (t < o) red[t] += red[t + o]; __syncthreads(); }
  if (t == 0) out[0] = red[0] / (float)NUM + 0.01f * (knn_acc[0] / (float)NUM);
}

extern "C" void kernel_launch(void* const* d_in, const int* in_sizes, int n_in,
                              void* d_out, int out_size, void* d_ws, size_t ws_size,
                              hipStream_t stream) {
  const float* x   = (const float*)d_in[0];
  const float* y   = (const float*)d_in[1];
  const float* lam = (const float*)d_in[2];
  const int* perm  = (const int*)d_in[3];
  float* ws = (float*)d_ws;

  float* n_all  = ws + OFF_NALL;
  float* y_all  = ws + OFF_YALL;
  float* rloss  = ws + OFF_RLOSS;
  float* ksq    = ws + OFF_KSQ;
  float* mu_sum = ws + OFF_MUSUM;
  float* counts = ws + OFF_CNT;
  float* knn_acc= ws + OFF_KNN;
  float* nmu    = ws + OFF_NMU;
  float* muT    = ws + OFF_MUT;
  float* tk1s   = ws + OFF_TK1S;
  int*   tk1i   = (int*)(ws + OFF_TK1I);
  float* tk2s   = ws + OFF_TK2S;
  int*   tk2i   = (int*)(ws + OFF_TK2I);
  _Float16* Xh  = (_Float16*)(ws + OFF_XH);

  bool fast = ws_size >= NEED_BYTES;   // constant per-process: same path every call

  k_y<<<(N0 + 255) / 256, 256, 0, stream>>>(y, y_all);
  k_norms<<<NUM, 64, 0, stream>>>(x, perm, lam, n_all);

  if (fast) {
    k_cvt<<<NUM, 128, 0, stream>>>(x, perm, lam, Xh);
    // mixup: queries rows N0..NUM (64/block), candidates rows 0..N0, 8 splits, top-16
    k_knn2<16><<<dim3(N0 / 64, 8), 256, 0, stream>>>(Xh, N0, n_all, N0 / 8, 8, tk1s, tk1i);
    k_rr1<<<N0, 256, 0, stream>>>(x, perm, lam, tk1s, tk1i, n_all, y, y_all);
    k_stats2<<<NCLS, 256, 0, stream>>>(x, perm, lam, y_all, muT, nmu, counts);
    // knn reg: all 8192 rows (64/block) vs all, 4 splits, top-8 (self + margin)
    k_knn2<8><<<dim3(NUM / 64, 4), 256, 0, stream>>>(Xh, 0, n_all, NUM / 4, 4, tk2s, tk2i);
    k_rr2<<<NUM, 256, 0, stream>>>(x, perm, lam, tk2s, tk2i, n_all, y_all, ksq);
    k_gm<<<NUM, 128, 0, stream>>>(x, perm, lam, y_all, n_all, muT, nmu, counts, rloss);
    k_final_fast<<<1, 256, 0, stream>>>(rloss, ksq, (float*)d_out);
  } else {
    k_zero<<<(ZERO_N + 255) / 256, 256, 0, stream>>>(mu_sum, ZERO_N);
    dim3 g1(N0 / QT, 4);
    k_knn_f32<KMIX><<<g1, 256, 0, stream>>>(x, perm, lam, N0, n_all, N0 / 4, 4, tk1s, tk1i);
    k_final1<<<(N0 + 255) / 256, 256, 0, stream>>>(tk1s, tk1i, y, y_all);
    k_stats<<<NUM, 128, 0, stream>>>(x, perm, lam, y_all, mu_sum, counts);
    k_mufin<<<NCLS, 256, 0, stream>>>(mu_sum, counts, muT, nmu);
    dim3 g2(NUM / QT, 2);
    k_knn_f32<4><<<g2, 256, 0, stream>>>(x, perm, lam, 0, n_all, NUM / 2, 2, tk2s, tk2i);
    k_final2<<<NUM / 256, 256, 0, stream>>>(tk2s, tk2i, y_all, knn_acc);
    k_gm<<<NUM, 128, 0, stream>>>(x, perm, lam, y_all, n_all, muT, nmu, counts, rloss);
    k_final_slow<<<1, 256, 0, stream>>>(rloss, knn_acc, (float*)d_out);
  }
}

// Round 5
// 699.124 us; speedup vs baseline: 4.3678x; 1.3283x over previous
//
#include <hip/hip_runtime.h>
#include <math.h>

#define N0   4096
#define D    512
#define NUM  8192
#define NCLS 100
#define KMIX 11

// ---- workspace layout (float offsets) ---- (identical span to R3/R4: 15.2 MB)
#define OFF_NALL   0            // [NUM]
#define OFF_YALL   8192         // [NUM]
#define OFF_RLOSS  16384        // [NUM]
#define OFF_KSQ    24576        // [NUM]
#define OFF_MUSUM  32768        // slow: [NCLS*D] f32 | fast: muH [128][512] f16 (32768 floats)
#define OFF_CNT    83968        // [128]
#define OFF_KNN    84096        // [1] slow-path scalar
#define ZERO_N     51344        // MUSUM..KNN inclusive (slow path)
#define OFF_NMU    84112        // slow nmu [NCLS]
#define OFF_MUT    84224        // slow: [D][NCLS] f32 | fast: nmu_pad [128]
#define OFF_TK1S   135424       // fast: [4096][8*16] / slow: [4096][4*11]
#define OFF_TK1I   659712
#define OFF_TK2S   1184000      // fast: [8192][4*8] / slow: [8192][2*4]
#define OFF_TK2I   1446144
#define OFF_XH     1708288      // [NUM][512] f16
#define TOTAL_F    3805440
#define NEED_BYTES ((size_t)TOTAL_F * 4)   // 15,221,760

typedef _Float16 half8 __attribute__((ext_vector_type(8)));
typedef _Float16 half4v __attribute__((ext_vector_type(4)));
typedef float f32x4 __attribute__((ext_vector_type(4)));
typedef unsigned long long u64;

// Logical row r of the virtual [NUM][D] matrix (bitwise-identical everywhere)
__device__ __forceinline__ float4 ld_row4(const float* __restrict__ x, const int* __restrict__ perm,
                                          float lam, float om, int r, int col) {
  if (r < N0) {
    return *(const float4*)(x + (size_t)r * D + col);
  } else {
    int rr = r - N0;
    int p = perm[rr];
    float4 a = *(const float4*)(x + (size_t)rr * D + col);
    float4 b = *(const float4*)(x + (size_t)p * D + col);
    float4 m;
    m.x = lam * a.x + om * b.x;  m.y = lam * a.y + om * b.y;
    m.z = lam * a.z + om * b.z;  m.w = lam * a.w + om * b.w;
    return m;
  }
}

__device__ __forceinline__ void gld_lds16(const _Float16* g, _Float16* l) {
  __builtin_amdgcn_global_load_lds(
      (const __attribute__((address_space(1))) void*)g,
      (__attribute__((address_space(3))) void*)l, 16, 0, 0);
}

__device__ __forceinline__ unsigned sortable(float s) {
  unsigned u = __float_as_uint(s);
  return ((int)u < 0) ? ~u : (u | 0x80000000u);
}
__device__ __forceinline__ float unsortable(unsigned u) {
  return __uint_as_float(((int)u < 0) ? (u & 0x7fffffffu) : ~u);
}

__global__ __launch_bounds__(256) void k_zero(float* __restrict__ p, int n) {
  int i = blockIdx.x * 256 + threadIdx.x;
  if (i < n) p[i] = 0.f;
}

__global__ __launch_bounds__(256) void k_y(const float* __restrict__ y, float* __restrict__ y_all) {
  int i = blockIdx.x * 256 + threadIdx.x;
  if (i < N0) y_all[i] = y[i];
}

// fused: y_all init + exact fp32 norms + f16 conversion (x loaded once)
__global__ __launch_bounds__(64) void k_prep(const float* __restrict__ x, const float* __restrict__ y,
                                             const int* __restrict__ perm, const float* __restrict__ lam_p,
                                             _Float16* __restrict__ Xh, float* __restrict__ n_all,
                                             float* __restrict__ y_all) {
  int i = blockIdx.x;
  float lam = lam_p[0], om = 1.0f - lam;
  int t = threadIdx.x;
  float4 a = ld_row4(x, perm, lam, om, i, t * 4);
  float4 b = ld_row4(x, perm, lam, om, i, t * 4 + 256);
  half4v ha, hb;
  ha.x = (_Float16)a.x; ha.y = (_Float16)a.y; ha.z = (_Float16)a.z; ha.w = (_Float16)a.w;
  hb.x = (_Float16)b.x; hb.y = (_Float16)b.y; hb.z = (_Float16)b.z; hb.w = (_Float16)b.w;
  *(half4v*)(Xh + (size_t)i * D + t * 4) = ha;
  *(half4v*)(Xh + (size_t)i * D + t * 4 + 256) = hb;
  float s = a.x*a.x + a.y*a.y + a.z*a.z + a.w*a.w
          + b.x*b.x + b.y*b.y + b.z*b.z + b.w*b.w;
  #pragma unroll
  for (int o = 32; o > 0; o >>= 1) s += __shfl_down(s, o, 64);
  if (t == 0) {
    n_all[i] = s;
    if (i < N0) y_all[i] = y[i];
  }
}

// ---- fused MFMA kNN body: 64q x 128c tile, BK=64, dbuf, frag-ordered LDS ----
// score = ||c||^2 - 2*dot_f16. Per-row top-M (u64 (score,idx) keys) per split.
// LDS: 2 staging bufs of 12288 halfs (Q 4 segs + C 8 segs); scores [128][68] f32
// and merge lists aliased inside. 49152 B total -> 3 blocks/CU.
template<int M, int NSPL>
__device__ __forceinline__ void knn_body(const _Float16* __restrict__ Xq,
                                         const _Float16* __restrict__ Xc,
                                         const float* __restrict__ nC,
                                         int cb0, int candPerSplit,
                                         int row0, int split,
                                         float* __restrict__ outS, int* __restrict__ outI,
                                         char* smem) {
  float* Ss = (float*)smem;
  _Float16* St = (_Float16*)smem;
  u64* Lb = (u64*)smem;

  int tid = threadIdx.x;
  int wave = tid >> 6, lane = tid & 63;
  int wq = wave >> 1, wc = wave & 1;     // wave tile: 32q x 64c
  int col16 = lane & 15, quad = lane >> 4;

  // staging: wave stages Q seg 'wave' and C segs 2*wave, 2*wave+1 (both chunks)
  const _Float16* qg = Xq + (size_t)(wave * 16 + col16) * D + quad * 8;
  int csegA = 2 * wave, csegB = 2 * wave + 1;
  int ldsQ = wave * 1024 + lane * 8;
  int ldsCA = 4096 + csegA * 1024 + lane * 8;
  int ldsCB = 4096 + csegB * 1024 + lane * 8;

  u64 keys[M];
  #pragma unroll
  for (int q = 0; q < M; q++) keys[q] = ~0ULL;

  int r_scan = tid & 63, h_scan = tid >> 6;

  for (int c0 = 0; c0 < candPerSplit; c0 += 128) {
    const _Float16* cgA = Xc + (size_t)(cb0 + c0 + csegA * 16 + col16) * D + quad * 8;
    const _Float16* cgB = cgA + (size_t)16 * D;

    f32x4 acc[2][4];
    #pragma unroll
    for (int i = 0; i < 2; i++)
      #pragma unroll
      for (int j = 0; j < 4; j++) acc[i][j] = (f32x4){0.f, 0.f, 0.f, 0.f};

    // prologue: kk=0 into buf0 (6 wave-instructions)
    gld_lds16(qg,       St + ldsQ);
    gld_lds16(qg + 32,  St + ldsQ + 512);
    gld_lds16(cgA,      St + ldsCA);
    gld_lds16(cgA + 32, St + ldsCA + 512);
    gld_lds16(cgB,      St + ldsCB);
    gld_lds16(cgB + 32, St + ldsCB + 512);
    __syncthreads();

    #pragma unroll
    for (int t = 0; t < 8; t++) {
      const int cur = t & 1;
      if (t < 7) {
        int kk = (t + 1) * 64;
        _Float16* B = St + (cur ^ 1) * 12288;
        gld_lds16(qg + kk,       B + ldsQ);
        gld_lds16(qg + kk + 32,  B + ldsQ + 512);
        gld_lds16(cgA + kk,      B + ldsCA);
        gld_lds16(cgA + kk + 32, B + ldsCA + 512);
        gld_lds16(cgB + kk,      B + ldsCB);
        gld_lds16(cgB + kk + 32, B + ldsCB + 512);
      }
      const _Float16* Bc = St + cur * 12288;
      half8 a[2][2], b[4][2];
      #pragma unroll
      for (int i = 0; i < 2; i++)
        #pragma unroll
        for (int h = 0; h < 2; h++)
          a[i][h] = *(const half8*)(Bc + (wq * 2 + i) * 1024 + h * 512 + lane * 8);
      #pragma unroll
      for (int j = 0; j < 4; j++)
        #pragma unroll
        for (int h = 0; h < 2; h++)
          b[j][h] = *(const half8*)(Bc + 4096 + (wc * 4 + j) * 1024 + h * 512 + lane * 8);
      #pragma unroll
      for (int h = 0; h < 2; h++)
        #pragma unroll
        for (int i = 0; i < 2; i++)
          #pragma unroll
          for (int j = 0; j < 4; j++)
            acc[i][j] = __builtin_amdgcn_mfma_f32_16x16x32_f16(a[i][h], b[j][h], acc[i][j], 0, 0, 0);
      __syncthreads();
    }

    // epilogue: transposed score store (C/D: col(c)=lane&15 grp, row(q)=quad*4+reg)
    #pragma unroll
    for (int j = 0; j < 4; j++) {
      int c_local = wc * 64 + j * 16 + col16;
      float ncv = nC[cb0 + c0 + c_local];
      #pragma unroll
      for (int i = 0; i < 2; i++) {
        float4 st;
        st.x = ncv - 2.f * acc[i][j][0];
        st.y = ncv - 2.f * acc[i][j][1];
        st.z = ncv - 2.f * acc[i][j][2];
        st.w = ncv - 2.f * acc[i][j][3];
        *(float4*)&Ss[(size_t)c_local * 68 + wq * 32 + i * 16 + quad * 4] = st;
      }
    }
    __syncthreads();

    // scan: 4 threads per query row, 32 candidates each, conflict-free b32
    for (int c = h_scan * 32; c < h_scan * 32 + 32; c++) {
      float s = Ss[c * 68 + r_scan];
      u64 key = ((u64)sortable(s) << 32) | (unsigned)(cb0 + c0 + c);
      if (key < keys[M - 1]) {
        keys[M - 1] = key;
        #pragma unroll
        for (int p = M - 1; p > 0; p--) {
          if (keys[p] < keys[p - 1]) { u64 tmp = keys[p]; keys[p] = keys[p - 1]; keys[p - 1] = tmp; }
        }
      }
    }
    __syncthreads();   // scan done before next prologue overwrites Ss/staging
  }

  // merge 4 partial lists per row -> sorted top-M for this split
  #pragma unroll
  for (int q = 0; q < M; q++)
    Lb[((size_t)h_scan * 64 + r_scan) * M + q] = keys[q];
  __syncthreads();
  if (tid < 64) {
    int p0 = 0, p1 = 0, p2 = 0, p3 = 0;
    const u64* L0 = Lb + (size_t)(0 * 64 + tid) * M;
    const u64* L1 = Lb + (size_t)(1 * 64 + tid) * M;
    const u64* L2 = Lb + (size_t)(2 * 64 + tid) * M;
    const u64* L3 = Lb + (size_t)(3 * 64 + tid) * M;
    size_t off = (size_t)(row0 + tid) * ((size_t)NSPL * M) + (size_t)split * M;
    #pragma unroll
    for (int q = 0; q < M; q++) {
      u64 k0 = (p0 < M) ? L0[p0] : ~0ULL;
      u64 k1 = (p1 < M) ? L1[p1] : ~0ULL;
      u64 k2 = (p2 < M) ? L2[p2] : ~0ULL;
      u64 k3 = (p3 < M) ? L3[p3] : ~0ULL;
      u64 b01 = k0 < k1 ? k0 : k1;
      u64 b23 = k2 < k3 ? k2 : k3;
      u64 b = b01 < b23 ? b01 : b23;
      if (b == k0) p0++; else if (b == k1) p1++; else if (b == k2) p2++; else p3++;
      outS[off + q] = unsortable((unsigned)(b >> 32));
      outI[off + q] = (int)(unsigned)b;
    }
  }
}

// one launch covers both kNN problems: blocks [0,512) = knn-reg (8 M, 4 splits),
// blocks [512,1024) = mixup (16 M, 8 splits). Long blocks first for tail packing.
__global__ __launch_bounds__(256, 3) void k_knn_all(const _Float16* __restrict__ Xh,
                                                    const float* __restrict__ n_all,
                                                    float* __restrict__ tk1s, int* __restrict__ tk1i,
                                                    float* __restrict__ tk2s, int* __restrict__ tk2i) {
  __shared__ __align__(16) char smem[49152];
  int bx = blockIdx.x;
  if (bx < 512) {            // knn regularizer: 8192 q vs 8192 c, 4 splits, top-8
    int qblk = bx & 127, split = bx >> 7;
    knn_body<8, 4>(Xh + (size_t)(qblk * 64) * D, Xh, n_all,
                   split * 2048, 2048, qblk * 64, split, tk2s, tk2i, smem);
  } else {                   // mixup: 4096 mixed q vs 4096 x c, 8 splits, top-16
    int b = bx - 512;
    int qblk = b & 63, split = b >> 6;
    knn_body<16, 8>(Xh + (size_t)(N0 + qblk * 64) * D, Xh, n_all,
                    split * 512, 512, qblk * 64, split, tk1s, tk1i, smem);
  }
}

// exact fp32 re-rank mixup: merge 8 split-lists(16) -> top-16 -> exact -> mode(11)
__global__ __launch_bounds__(256) void k_rr1(const float* __restrict__ x, const int* __restrict__ perm,
                                             const float* __restrict__ lam_p,
                                             const float* __restrict__ tks, const int* __restrict__ tki,
                                             const float* __restrict__ n_all, const float* __restrict__ y,
                                             float* __restrict__ y_all) {
  __shared__ int sidx[16];
  __shared__ float sdot[16];
  int i = blockIdx.x;
  int t = threadIdx.x;
  float lam = lam_p[0], om = 1.f - lam;
  if (t == 0) {
    const float* sb = tks + (size_t)i * 128;
    const int* ib = tki + (size_t)i * 128;
    int p[8] = {0,0,0,0,0,0,0,0};
    for (int q = 0; q < 16; q++) {
      float bs = 3.0e38f; int bi = 0x7fffffff; int w = 0;
      #pragma unroll
      for (int li = 0; li < 8; li++) {
        if (p[li] < 16) {
          float s = sb[li * 16 + p[li]]; int id = ib[li * 16 + p[li]];
          if (s < bs || (s == bs && id < bi)) { bs = s; bi = id; w = li; }
        }
      }
      p[w]++;
      sidx[q] = bi;
    }
  }
  __syncthreads();
  int g = t >> 4, l16 = t & 15;
  int c = sidx[g];
  float dot = 0.f;
  for (int d0 = l16 * 4; d0 < D; d0 += 64) {
    float4 q4 = ld_row4(x, perm, lam, om, N0 + i, d0);
    float4 c4 = *(const float4*)(x + (size_t)c * D + d0);
    dot += q4.x*c4.x + q4.y*c4.y + q4.z*c4.z + q4.w*c4.w;
  }
  #pragma unroll
  for (int o = 8; o > 0; o >>= 1) dot += __shfl_down(dot, o, 16);
  if (l16 == 0) sdot[g] = n_all[c] - 2.f * dot;
  __syncthreads();
  if (t == 0) {
    float es[16]; int ei[16];
    for (int q = 0; q < 16; q++) { es[q] = sdot[q]; ei[q] = sidx[q]; }
    for (int a = 1; a < 16; a++) {
      float s = es[a]; int id = ei[a];
      int b = a - 1;
      while (b >= 0 && (es[b] > s || (es[b] == s && ei[b] > id))) {
        es[b + 1] = es[b]; ei[b + 1] = ei[b]; b--;
      }
      es[b + 1] = s; ei[b + 1] = id;
    }
    float lab[KMIX];
    for (int q = 0; q < KMIX; q++) lab[q] = y[ei[q]];
    float best = 3.0e38f; int bestc = 0;
    for (int q = 0; q < KMIX; q++) {
      int cnt = 0;
      for (int r = 0; r < KMIX; r++) cnt += (lab[r] == lab[q]) ? 1 : 0;
      if (cnt > bestc || (cnt == bestc && lab[q] < best)) { bestc = cnt; best = lab[q]; }
    }
    y_all[N0 + i] = best;
  }
}

// exact fp32 re-rank knn reg: merge 4 split-lists(8) -> top-8 -> exact -> drop self, mode(3)
__global__ __launch_bounds__(256) void k_rr2(const float* __restrict__ x, const int* __restrict__ perm,
                                             const float* __restrict__ lam_p,
                                             const float* __restrict__ tks, const int* __restrict__ tki,
                                             const float* __restrict__ n_all, const float* __restrict__ y_all,
                                             float* __restrict__ ksq) {
  __shared__ int sidx[8];
  __shared__ float sdot[8];
  int i = blockIdx.x;
  int t = threadIdx.x;
  float lam = lam_p[0], om = 1.f - lam;
  if (t == 0) {
    const float* sb = tks + (size_t)i * 32;
    const int* ib = tki + (size_t)i * 32;
    int p[4] = {0,0,0,0};
    for (int q = 0; q < 8; q++) {
      float bs = 3.0e38f; int bi = 0x7fffffff; int w = 0;
      #pragma unroll
      for (int li = 0; li < 4; li++) {
        if (p[li] < 8) {
          float s = sb[li * 8 + p[li]]; int id = ib[li * 8 + p[li]];
          if (s < bs || (s == bs && id < bi)) { bs = s; bi = id; w = li; }
        }
      }
      p[w]++;
      sidx[q] = bi;
    }
  }
  __syncthreads();
  int g = t >> 5, l32 = t & 31;
  int c = sidx[g];
  float dot = 0.f;
  for (int d0 = l32 * 4; d0 < D; d0 += 128) {
    float4 q4 = ld_row4(x, perm, lam, om, i, d0);
    float4 c4 = ld_row4(x, perm, lam, om, c, d0);
    dot += q4.x*c4.x + q4.y*c4.y + q4.z*c4.z + q4.w*c4.w;
  }
  #pragma unroll
  for (int o = 16; o > 0; o >>= 1) dot += __shfl_down(dot, o, 32);
  if (l32 == 0) sdot[g] = n_all[c] - 2.f * dot;
  __syncthreads();
  if (t == 0) {
    float es[8]; int ei[8];
    for (int q = 0; q < 8; q++) { es[q] = sdot[q]; ei[q] = sidx[q]; }
    for (int a = 1; a < 8; a++) {
      float s = es[a]; int id = ei[a];
      int b = a - 1;
      while (b >= 0 && (es[b] > s || (es[b] == s && ei[b] > id))) {
        es[b + 1] = es[b]; ei[b + 1] = ei[b]; b--;
      }
      es[b + 1] = s; ei[b + 1] = id;
    }
    float l1 = y_all[ei[1]], l2 = y_all[ei[2]], l3 = y_all[ei[3]];
    int c1 = 1 + (int)(l2 == l1) + (int)(l3 == l1);
    int c2 = 1 + (int)(l1 == l2) + (int)(l3 == l2);
    int c3 = 1 + (int)(l1 == l3) + (int)(l2 == l3);
    int mc = c1 > c2 ? c1 : c2; mc = mc > c3 ? mc : c3;
    float mv = 3.0e38f;
    if (c1 == mc) mv = fminf(mv, l1);
    if (c2 == mc) mv = fminf(mv, l2);
    if (c3 == mc) mv = fminf(mv, l3);
    float d = mv - y_all[i];
    ksq[i] = d * d;
  }
}

// per-class mean via LDS row-list; writes f16 muH [128][512] (pad rows zeroed),
// nmu_pad[128], counts[128]. f16 rounding of mu is exact-output-invariant:
// min d2 ~ 250 >> 176 (f32 exp underflow) => pi == 0 regardless of +-1 d2 error.
__global__ __launch_bounds__(256) void k_stats2h(const float* __restrict__ x, const int* __restrict__ perm,
                                                 const float* __restrict__ lam_p, const float* __restrict__ y_all,
                                                 _Float16* __restrict__ muH, float* __restrict__ nmu_pad,
                                                 float* __restrict__ counts) {
  __shared__ int cnt;
  __shared__ int lst[NUM];
  __shared__ int lstp[NUM];
  __shared__ float red[256];
  int c = blockIdx.x;
  int t = threadIdx.x;
  if (c >= NCLS) {
    for (int d = t; d < D; d += 256) muH[(size_t)c * D + d] = (_Float16)0.f;
    if (t == 0) { nmu_pad[c] = 0.f; counts[c] = 0.f; }
    return;
  }
  float lam = lam_p[0], om = 1.f - lam;
  float fc = (float)c;
  if (t == 0) cnt = 0;
  __syncthreads();
  for (int i = t; i < NUM; i += 256) {
    if (y_all[i] == fc) {
      int pos = atomicAdd(&cnt, 1);
      lst[pos] = i;
      lstp[pos] = (i >= N0) ? perm[i - N0] : 0;
    }
  }
  __syncthreads();
  int n = cnt;
  float a0 = 0.f, a1 = 0.f;
  for (int m = 0; m < n; m++) {
    int i = lst[m];
    if (i < N0) {
      a0 += x[(size_t)i * D + t];
      a1 += x[(size_t)i * D + t + 256];
    } else {
      int rr = i - N0, p = lstp[m];
      a0 += lam * x[(size_t)rr * D + t] + om * x[(size_t)p * D + t];
      a1 += lam * x[(size_t)rr * D + t + 256] + om * x[(size_t)p * D + t + 256];
    }
  }
  float inv = 1.f / fmaxf((float)n, 1.f);
  float v0 = a0 * inv, v1 = a1 * inv;
  muH[(size_t)c * D + t] = (_Float16)v0;
  muH[(size_t)c * D + t + 256] = (_Float16)v1;
  red[t] = v0 * v0 + v1 * v1;
  __syncthreads();
  for (int o = 128; o > 0; o >>= 1) { if (t < o) red[t] += red[t + o]; __syncthreads(); }
  if (t == 0) { nmu_pad[c] = red[0]; counts[c] = (float)n; }
}

// GM loss via MFMA GEMM (64 rows x 128 padded classes per block) + per-row
// closed-form pi reduction. Same underflow-exact semantics as R2-R4 k_gm.
__global__ __launch_bounds__(256) void k_gm2(const _Float16* __restrict__ Xh,
                                             const _Float16* __restrict__ muH,
                                             const float* __restrict__ nmu_pad,
                                             const float* __restrict__ counts,
                                             const float* __restrict__ n_all,
                                             const float* __restrict__ y_all,
                                             float* __restrict__ rloss) {
  __shared__ __align__(16) char smem[49152];
  float* Ss = (float*)smem;
  _Float16* St = (_Float16*)smem;

  int tid = threadIdx.x;
  int wave = tid >> 6, lane = tid & 63;
  int wq = wave >> 1, wc = wave & 1;
  int col16 = lane & 15, quad = lane >> 4;
  int qb = blockIdx.x * 64;

  const _Float16* qg = Xh + (size_t)(qb + wave * 16 + col16) * D + quad * 8;
  int csegA = 2 * wave, csegB = 2 * wave + 1;
  const _Float16* cgA = muH + (size_t)(csegA * 16 + col16) * D + quad * 8;
  const _Float16* cgB = cgA + (size_t)16 * D;
  int ldsQ = wave * 1024 + lane * 8;
  int ldsCA = 4096 + csegA * 1024 + lane * 8;
  int ldsCB = 4096 + csegB * 1024 + lane * 8;

  f32x4 acc[2][4];
  #pragma unroll
  for (int i = 0; i < 2; i++)
    #pragma unroll
    for (int j = 0; j < 4; j++) acc[i][j] = (f32x4){0.f, 0.f, 0.f, 0.f};

  gld_lds16(qg,       St + ldsQ);
  gld_lds16(qg + 32,  St + ldsQ + 512);
  gld_lds16(cgA,      St + ldsCA);
  gld_lds16(cgA + 32, St + ldsCA + 512);
  gld_lds16(cgB,      St + ldsCB);
  gld_lds16(cgB + 32, St + ldsCB + 512);
  __syncthreads();

  #pragma unroll
  for (int t = 0; t < 8; t++) {
    const int cur = t & 1;
    if (t < 7) {
      int kk = (t + 1) * 64;
      _Float16* B = St + (cur ^ 1) * 12288;
      gld_lds16(qg + kk,       B + ldsQ);
      gld_lds16(qg + kk + 32,  B + ldsQ + 512);
      gld_lds16(cgA + kk,      B + ldsCA);
      gld_lds16(cgA + kk + 32, B + ldsCA + 512);
      gld_lds16(cgB + kk,      B + ldsCB);
      gld_lds16(cgB + kk + 32, B + ldsCB + 512);
    }
    const _Float16* Bc = St + cur * 12288;
    half8 a[2][2], b[4][2];
    #pragma unroll
    for (int i = 0; i < 2; i++)
      #pragma unroll
      for (int h = 0; h < 2; h++)
        a[i][h] = *(const half8*)(Bc + (wq * 2 + i) * 1024 + h * 512 + lane * 8);
    #pragma unroll
    for (int j = 0; j < 4; j++)
      #pragma unroll
      for (int h = 0; h < 2; h++)
        b[j][h] = *(const half8*)(Bc + 4096 + (wc * 4 + j) * 1024 + h * 512 + lane * 8);
    #pragma unroll
    for (int h = 0; h < 2; h++)
      #pragma unroll
      for (int i = 0; i < 2; i++)
        #pragma unroll
        for (int j = 0; j < 4; j++)
          acc[i][j] = __builtin_amdgcn_mfma_f32_16x16x32_f16(a[i][h], b[j][h], acc[i][j], 0, 0, 0);
    __syncthreads();
  }

  // scores s_c = nmu[c] - 2*dot  (row-const n_all added at the end)
  #pragma unroll
  for (int j = 0; j < 4; j++) {
    int c_local = wc * 64 + j * 16 + col16;
    float ncv = nmu_pad[c_local];
    #pragma unroll
    for (int i = 0; i < 2; i++) {
      float4 st;
      st.x = ncv - 2.f * acc[i][j][0];
      st.y = ncv - 2.f * acc[i][j][1];
      st.z = ncv - 2.f * acc[i][j][2];
      st.w = ncv - 2.f * acc[i][j][3];
      *(float4*)&Ss[(size_t)c_local * 68 + wq * 32 + i * 16 + quad * 4] = st;
    }
  }
  __syncthreads();

  // per-row reduction: 4 threads/row over 32 classes each
  int r = tid & 63, h = tid >> 6;
  float* redm = (float*)(smem + 35840);   // [4][64]
  float* mrow = (float*)(smem + 36864);   // [64]
  float* Sp   = (float*)(smem + 37120);   // [4][64]
  float* Ep   = (float*)(smem + 38144);   // [4][64]
  float* Yp   = (float*)(smem + 39168);   // [4][64]

  float mymin = 3.0e38f;
  for (int c = h * 32; c < h * 32 + 32; c++) {
    if (c < NCLS && counts[c] > 0.f) mymin = fminf(mymin, Ss[c * 68 + r]);
  }
  redm[h * 64 + r] = mymin;
  __syncthreads();
  if (tid < 64) {
    float ms = fminf(fminf(redm[tid], redm[64 + tid]), fminf(redm[128 + tid], redm[192 + tid]));
    mrow[tid] = ms;
  }
  __syncthreads();
  float ms = mrow[r];
  int yc = (int)y_all[qb + r];
  float Sv = 0.f, Se2 = 0.f, ey = 0.f;
  for (int c = h * 32; c < h * 32 + 32; c++) {
    if (c < NCLS && counts[c] > 0.f) {
      float e = expf(-0.5f * (Ss[c * 68 + r] - ms));
      Sv += e; Se2 += e * e;
      if (c == yc) ey = e;
    }
  }
  Sp[h * 64 + r] = Sv; Ep[h * 64 + r] = Se2; Yp[h * 64 + r] = ey;
  __syncthreads();
  if (tid < 64) {
    float S4 = Sp[tid] + Sp[64 + tid] + Sp[128 + tid] + Sp[192 + tid];
    float E4 = Ep[tid] + Ep[64 + tid] + Ep[128 + tid] + Ep[192 + tid];
    float Y4 = Yp[tid] + Yp[64 + tid] + Yp[128 + tid] + Yp[192 + tid];
    float m = n_all[qb + tid] + mrow[tid];
    float E = expf(-0.5f * m);          // underflows to 0 -> pi == 0 -> loss 1
    float denom = E * S4 + 1e-15f;
    float f = E / denom;
    rloss[qb + tid] = E4 * f * f - 2.f * Y4 * f + 1.f;
  }
}

__global__ __launch_bounds__(256) void k_final_fast(const float* __restrict__ row_loss,
                                                    const float* __restrict__ ksq, float* __restrict__ out) {
  __shared__ float red[256];
  int t = threadIdx.x;
  float s = 0.f;
  for (int i = t; i < NUM; i += 256) s += row_loss[i] + 0.01f * ksq[i];
  red[t] = s;
  __syncthreads();
  for (int o = 128; o > 0; o >>= 1) { if (t < o) red[t] += red[t + o]; __syncthreads(); }
  if (t == 0) out[0] = red[0] / (float)NUM;
}

// ================= fp32 fallback path (R2, passed absmax 0.0) =================
#define QT 32
#define CTF 128
#define BKF 32

__global__ __launch_bounds__(64) void k_norms(const float* __restrict__ x, const int* __restrict__ perm,
                                              const float* __restrict__ lam_p, float* __restrict__ n_all) {
  int i = blockIdx.x;
  float lam = lam_p[0], om = 1.0f - lam;
  int t = threadIdx.x;
  float4 a = ld_row4(x, perm, lam, om, i, t * 4);
  float4 b = ld_row4(x, perm, lam, om, i, t * 4 + 256);
  float s = a.x*a.x + a.y*a.y + a.z*a.z + a.w*a.w
          + b.x*b.x + b.y*b.y + b.z*b.z + b.w*b.w;
  #pragma unroll
  for (int o = 32; o > 0; o >>= 1) s += __shfl_down(s, o, 64);
  if (t == 0) n_all[i] = s;
}

template<int KK>
__global__ __launch_bounds__(256) void k_knn_f32(const float* __restrict__ x, const int* __restrict__ perm,
                                                 const float* __restrict__ lam_p, int qstart,
                                                 const float* __restrict__ nC, int candPerSplit, int nsplits,
                                                 float* __restrict__ outS, int* __restrict__ outI) {
  __shared__ float Qs[BKF][QT + 4];
  __shared__ float Cs[BKF][CTF + 4];
  __shared__ float Sf[QT][CTF + 4];

  int tid = threadIdx.x;
  float lam = lam_p[0], om = 1.0f - lam;
  int qbase = blockIdx.x * QT;
  int cb = blockIdx.y * candPerSplit;
  int ce = cb + candPerSplit;

  int cx = tid & 31;
  int ry = tid >> 5;
  int lr = tid >> 3;
  int kc = (tid & 7) * 4;

  float ks[KK]; int ki[KK];
  #pragma unroll
  for (int q = 0; q < KK; q++) { ks[q] = 3.0e38f; ki[q] = 0x7fffffff; }

  for (int c0 = cb; c0 < ce; c0 += CTF) {
    float acc[4][4];
    #pragma unroll
    for (int i = 0; i < 4; i++)
      #pragma unroll
      for (int j = 0; j < 4; j++) acc[i][j] = 0.f;

    for (int kk = 0; kk < D; kk += BKF) {
      __syncthreads();
      {
        float4 v = ld_row4(x, perm, lam, om, qstart + qbase + lr, kk + kc);
        Qs[kc + 0][lr] = v.x; Qs[kc + 1][lr] = v.y; Qs[kc + 2][lr] = v.z; Qs[kc + 3][lr] = v.w;
      }
      #pragma unroll
      for (int rr = 0; rr < 4; rr++) {
        int r = lr + rr * 32;
        float4 v = ld_row4(x, perm, lam, om, c0 + r, kk + kc);
        Cs[kc + 0][r] = v.x; Cs[kc + 1][r] = v.y; Cs[kc + 2][r] = v.z; Cs[kc + 3][r] = v.w;
      }
      __syncthreads();
      #pragma unroll
      for (int k = 0; k < BKF; k++) {
        float4 a4 = *(const float4*)&Qs[k][ry * 4];
        float4 b4 = *(const float4*)&Cs[k][cx * 4];
        float av[4] = {a4.x, a4.y, a4.z, a4.w};
        float bv[4] = {b4.x, b4.y, b4.z, b4.w};
        #pragma unroll
        for (int i = 0; i < 4; i++)
          #pragma unroll
          for (int j = 0; j < 4; j++) acc[i][j] += av[i] * bv[j];
      }
    }
    __syncthreads();
    {
      float4 nc4 = *(const float4*)&nC[c0 + cx * 4];
      float ncv[4] = {nc4.x, nc4.y, nc4.z, nc4.w};
      #pragma unroll
      for (int i = 0; i < 4; i++)
        #pragma unroll
        for (int j = 0; j < 4; j++)
          Sf[ry * 4 + i][cx * 4 + j] = ncv[j] - 2.0f * acc[i][j];
    }
    __syncthreads();
    if (tid < QT) {
      for (int c = 0; c < CTF; c++) {
        float s = Sf[tid][c];
        int j = c0 + c;
        bool worse = (s > ks[KK - 1]) || (s == ks[KK - 1] && j > ki[KK - 1]);
        if (!worse) {
          ks[KK - 1] = s; ki[KK - 1] = j;
          #pragma unroll
          for (int p = KK - 1; p > 0; p--) {
            bool sw = (ks[p] < ks[p - 1]) || (ks[p] == ks[p - 1] && ki[p] < ki[p - 1]);
            if (sw) {
              float ts = ks[p]; ks[p] = ks[p - 1]; ks[p - 1] = ts;
              int ti = ki[p]; ki[p] = ki[p - 1]; ki[p - 1] = ti;
            }
          }
        }
      }
    }
  }

  if (tid < QT) {
    int row = qbase + tid;
    size_t off = (size_t)row * (nsplits * KK) + (size_t)blockIdx.y * KK;
    #pragma unroll
    for (int q = 0; q < KK; q++) { outS[off + q] = ks[q]; outI[off + q] = ki[q]; }
  }
}

__global__ __launch_bounds__(256) void k_final1(const float* __restrict__ tks, const int* __restrict__ tki,
                                                const float* __restrict__ y, float* __restrict__ y_all) {
  int i = blockIdx.x * 256 + threadIdx.x;
  if (i >= N0) return;
  const float* sb = tks + (size_t)i * 44;
  const int* ib = tki + (size_t)i * 44;
  int p0 = 0, p1 = 0, p2 = 0, p3 = 0;
  float lab[KMIX];
  #pragma unroll
  for (int q = 0; q < KMIX; q++) {
    float bs = 3.0e38f; int bi = 0x7fffffff; int w = 0;
    if (p0 < 11) { float s = sb[p0];      int id = ib[p0];      if (s < bs || (s == bs && id < bi)) { bs = s; bi = id; w = 0; } }
    if (p1 < 11) { float s = sb[11 + p1]; int id = ib[11 + p1]; if (s < bs || (s == bs && id < bi)) { bs = s; bi = id; w = 1; } }
    if (p2 < 11) { float s = sb[22 + p2]; int id = ib[22 + p2]; if (s < bs || (s == bs && id < bi)) { bs = s; bi = id; w = 2; } }
    if (p3 < 11) { float s = sb[33 + p3]; int id = ib[33 + p3]; if (s < bs || (s == bs && id < bi)) { bs = s; bi = id; w = 3; } }
    if (w == 0) p0++; else if (w == 1) p1++; else if (w == 2) p2++; else p3++;
    lab[q] = y[bi];
  }
  float best = 3.0e38f; int bestc = 0;
  #pragma unroll
  for (int q = 0; q < KMIX; q++) {
    int c = 0;
    #pragma unroll
    for (int r = 0; r < KMIX; r++) c += (lab[r] == lab[q]) ? 1 : 0;
    if (c > bestc || (c == bestc && lab[q] < best)) { bestc = c; best = lab[q]; }
  }
  y_all[N0 + i] = best;
}

__global__ __launch_bounds__(128) void k_stats(const float* __restrict__ x, const int* __restrict__ perm,
                                               const float* __restrict__ lam_p, const float* __restrict__ y_all,
                                               float* __restrict__ mu_sum, float* __restrict__ counts) {
  int i = blockIdx.x;
  float lam = lam_p[0], om = 1.0f - lam;
  int c = (int)y_all[i];
  float* ms = mu_sum + (size_t)c * D;
  int t = threadIdx.x;
  float4 v = ld_row4(x, perm, lam, om, i, t * 4);
  atomicAdd(&ms[t * 4 + 0], v.x);
  atomicAdd(&ms[t * 4 + 1], v.y);
  atomicAdd(&ms[t * 4 + 2], v.z);
  atomicAdd(&ms[t * 4 + 3], v.w);
  if (t == 0) atomicAdd(&counts[c], 1.0f);
}

__global__ __launch_bounds__(256) void k_mufin(const float* __restrict__ mu_sum, const float* __restrict__ counts,
                                               float* __restrict__ muT, float* __restrict__ nmu) {
  __shared__ float red[256];
  int c = blockIdx.x;
  float inv = 1.0f / fmaxf(counts[c], 1.0f);
  int t = threadIdx.x;
  float v0 = mu_sum[(size_t)c * D + t] * inv;
  float v1 = mu_sum[(size_t)c * D + t + 256] * inv;
  muT[(size_t)t * NCLS + c] = v0;
  muT[(size_t)(t + 256) * NCLS + c] = v1;
  red[t] = v0 * v0 + v1 * v1;
  __syncthreads();
  for (int o = 128; o > 0; o >>= 1) { if (t < o) red[t] += red[t + o]; __syncthreads(); }
  if (t == 0) nmu[c] = red[0];
}

__global__ __launch_bounds__(256) void k_final2(const float* __restrict__ t2s, const int* __restrict__ t2i,
                                                const float* __restrict__ y_all, float* __restrict__ knn_acc) {
  __shared__ float red[256];
  int i = blockIdx.x * 256 + threadIdx.x;
  float dd2 = 0.f;
  if (i < NUM) {
    const float* sA = t2s + (size_t)i * 8; const float* sB = sA + 4;
    const int* iA = t2i + (size_t)i * 8;   const int* iB = iA + 4;
    int pa = 0, pb = 0;
    int midx[4];
    #pragma unroll
    for (int q = 0; q < 4; q++) {
      float sa = (pa < 4) ? sA[pa] : 3.0e38f;
      float sb = (pb < 4) ? sB[pb] : 3.0e38f;
      int ia = (pa < 4) ? iA[pa] : 0x7fffffff;
      int ib = (pb < 4) ? iB[pb] : 0x7fffffff;
      bool ta = (sa < sb) || (sa == sb && ia < ib);
      midx[q] = ta ? ia : ib;
      if (ta) pa++; else pb++;
    }
    float l1 = y_all[midx[1]], l2 = y_all[midx[2]], l3 = y_all[midx[3]];
    int c1 = 1 + (int)(l2 == l1) + (int)(l3 == l1);
    int c2 = 1 + (int)(l1 == l2) + (int)(l3 == l2);
    int c3 = 1 + (int)(l1 == l3) + (int)(l2 == l3);
    int mc = c1 > c2 ? c1 : c2; mc = mc > c3 ? mc : c3;
    float mv = 3.0e38f;
    if (c1 == mc) mv = fminf(mv, l1);
    if (c2 == mc) mv = fminf(mv, l2);
    if (c3 == mc) mv = fminf(mv, l3);
    float d = mv - y_all[i];
    dd2 = d * d;
  }
  red[threadIdx.x] = dd2;
  __syncthreads();
  for (int o = 128; o > 0; o >>= 1) { if (threadIdx.x < o) red[threadIdx.x] += red[threadIdx.x + o]; __syncthreads(); }
  if (threadIdx.x == 0) atomicAdd(knn_acc, red[0]);
}

__global__ __launch_bounds__(128) void k_gm(const float* __restrict__ x, const int* __restrict__ perm,
                                            const float* __restrict__ lam_p, const float* __restrict__ y_all,
                                            const float* __restrict__ n_all, const float* __restrict__ muT,
                                            const float* __restrict__ nmu, const float* __restrict__ counts,
                                            float* __restrict__ row_loss) {
  __shared__ float red[128];
  int i = blockIdx.x;
  int t = threadIdx.x;
  float lam = lam_p[0], om = 1.0f - lam;
  bool valid = (t < NCLS) && (counts[t] > 0.f);
  float d2 = 3.0e38f;
  if (t < NCLS) {
    float dot = 0.f;
    for (int d = 0; d < D; d += 4) {
      float4 v = ld_row4(x, perm, lam, om, i, d);
      dot += v.x * muT[(size_t)(d + 0) * NCLS + t];
      dot += v.y * muT[(size_t)(d + 1) * NCLS + t];
      dot += v.z * muT[(size_t)(d + 2) * NCLS + t];
      dot += v.w * muT[(size_t)(d + 3) * NCLS + t];
    }
    d2 = n_all[i] + nmu[t] - 2.f * dot;
  }
  red[t] = valid ? d2 : 3.0e38f;
  __syncthreads();
  for (int o = 64; o > 0; o >>= 1) { if (t < o) red[t] = fminf(red[t], red[t + o]); __syncthreads(); }
  float m = red[0];
  __syncthreads();
  float e = valid ? expf(-0.5f * (d2 - m)) : 0.f;
  red[t] = e;
  __syncthreads();
  for (int o = 64; o > 0; o >>= 1) { if (t < o) red[t] += red[t + o]; __syncthreads(); }
  float S = red[0];
  __syncthreads();
  float E = expf(-0.5f * m);
  float denom = E * S + 1e-15f;
  float pi = e * E / denom;
  pi = fminf(fmaxf(pi, 0.f), 1.f);
  int yc = (int)y_all[i];
  float term = pi * pi - 2.f * ((t == yc) ? pi : 0.f);
  red[t] = valid ? term : 0.f;
  __syncthreads();
  for (int o = 64; o > 0; o >>= 1) { if (t < o) red[t] += red[t + o]; __syncthreads(); }
  if (t == 0) row_loss[i] = red[0] + 1.0f;
}

__global__ __launch_bounds__(256) void k_final_slow(const float* __restrict__ row_loss,
                                                    const float* __restrict__ knn_acc, float* __restrict__ out) {
  __shared__ float red[256];
  int t = threadIdx.x;
  float s = 0.f;
  for (int i = t; i < NUM; i += 256) s += row_loss[i];
  red[t] = s;
  __syncthreads();
  for (int o = 128; o > 0; o >>= 1) { if (t < o) red[t] += red[t + o]; __syncthreads(); }
  if (t == 0) out[0] = red[0] / (float)NUM + 0.01f * (knn_acc[0] / (float)NUM);
}

extern "C" void kernel_launch(void* const* d_in, const int* in_sizes, int n_in,
                              void* d_out, int out_size, void* d_ws, size_t ws_size,
                              hipStream_t stream) {
  const float* x   = (const float*)d_in[0];
  const float* y   = (const float*)d_in[1];
  const float* lam = (const float*)d_in[2];
  const int* perm  = (const int*)d_in[3];
  float* ws = (float*)d_ws;

  float* n_all  = ws + OFF_NALL;
  float* y_all  = ws + OFF_YALL;
  float* rloss  = ws + OFF_RLOSS;
  float* ksq    = ws + OFF_KSQ;
  float* mu_sum = ws + OFF_MUSUM;
  float* counts = ws + OFF_CNT;
  float* knn_acc= ws + OFF_KNN;
  float* nmu    = ws + OFF_NMU;
  float* muT    = ws + OFF_MUT;
  float* tk1s   = ws + OFF_TK1S;
  int*   tk1i   = (int*)(ws + OFF_TK1I);
  float* tk2s   = ws + OFF_TK2S;
  int*   tk2i   = (int*)(ws + OFF_TK2I);
  _Float16* Xh  = (_Float16*)(ws + OFF_XH);
  _Float16* muH = (_Float16*)(ws + OFF_MUSUM);   // fast path: 32768 floats of MUSUM
  float* nmu_pad= ws + OFF_MUT;                  // fast path: 128 floats of MUT

  bool fast = ws_size >= NEED_BYTES;   // constant per-process: same path every call

  if (fast) {
    k_prep<<<NUM, 64, 0, stream>>>(x, y, perm, lam, Xh, n_all, y_all);
    k_knn_all<<<1024, 256, 0, stream>>>(Xh, n_all, tk1s, tk1i, tk2s, tk2i);
    k_rr1<<<N0, 256, 0, stream>>>(x, perm, lam, tk1s, tk1i, n_all, y, y_all);
    k_stats2h<<<128, 256, 0, stream>>>(x, perm, lam, y_all, muH, nmu_pad, counts);
    k_rr2<<<NUM, 256, 0, stream>>>(x, perm, lam, tk2s, tk2i, n_all, y_all, ksq);
    k_gm2<<<NUM / 64, 256, 0, stream>>>(Xh, muH, nmu_pad, counts, n_all, y_all, rloss);
    k_final_fast<<<1, 256, 0, stream>>>(rloss, ksq, (float*)d_out);
  } else {
    k_y<<<(N0 + 255) / 256, 256, 0, stream>>>(y, y_all);
    k_zero<<<(ZERO_N + 255) / 256, 256, 0, stream>>>(mu_sum, ZERO_N);
    k_norms<<<NUM, 64, 0, stream>>>(x, perm, lam, n_all);
    dim3 g1(N0 / QT, 4);
    k_knn_f32<KMIX><<<g1, 256, 0, stream>>>(x, perm, lam, N0, n_all, N0 / 4, 4, tk1s, tk1i);
    k_final1<<<(N0 + 255) / 256, 256, 0, stream>>>(tk1s, tk1i, y, y_all);
    k_stats<<<NUM, 128, 0, stream>>>(x, perm, lam, y_all, mu_sum, counts);
    k_mufin<<<NCLS, 256, 0, stream>>>(mu_sum, counts, muT, nmu);
    dim3 g2(NUM / QT, 2);
    k_knn_f32<4><<<g2, 256, 0, stream>>>(x, perm, lam, 0, n_all, NUM / 2, 2, tk2s, tk2i);
    k_final2<<<NUM / 256, 256, 0, stream>>>(tk2s, tk2i, y_all, knn_acc);
    k_gm<<<NUM, 128, 0, stream>>>(x, perm, lam, y_all, n_all, muT, nmu, counts, rloss);
    k_final_slow<<<1, 256, 0, stream>>>(rloss, knn_acc, (float*)d_out);
  }
}